// Round 1
// baseline (4376.139 us; speedup 1.0000x reference)
//
#include <hip/hip_runtime.h>
#include <hip/hip_bf16.h>

// Problem constants
#define B_   2
#define S_   2048
#define HD_  2048
#define H_   4
#define DK_  256
#define DV_  512
#define KD_  1024   // H_*DK_
#define VD_  2048   // H_*DV_
#define M_   4096   // B_*S_
#define NCHUNK_ 32
#define CHUNK_  64

// ---------------------------------------------------------------------------
// Generic fp32 tiled GEMM: C[M][N] = A[M][K] @ B[K][N]. 64x64 tile, 256 thr,
// 4x4 per thread, K-tile 16. M,N,K must be multiples of 64/64/16.
// ---------------------------------------------------------------------------
__global__ __launch_bounds__(256) void gemm64(const float* __restrict__ A,
                                              const float* __restrict__ B,
                                              float* __restrict__ C,
                                              int M, int N, int K) {
    __shared__ float As[16][65];
    __shared__ float Bs[16][65];
    const int tid = threadIdx.x;
    const int m0 = blockIdx.y * 64;
    const int n0 = blockIdx.x * 64;
    const int tx = tid & 15, ty = tid >> 4;
    float acc[4][4] = {};

    for (int k0 = 0; k0 < K; k0 += 16) {
        // A tile: 64 rows x 16 k
        {
            const int kk = tid & 15;
            const int mb = tid >> 4;
#pragma unroll
            for (int p = 0; p < 4; ++p) {
                int m = mb + p * 16;
                As[kk][m] = A[(size_t)(m0 + m) * K + k0 + kk];
            }
            const int n = tid & 63;
            const int kb = tid >> 6;
#pragma unroll
            for (int p = 0; p < 4; ++p) {
                int kk2 = kb * 4 + p;
                Bs[kk2][n] = B[(size_t)(k0 + kk2) * N + n0 + n];
            }
        }
        __syncthreads();
#pragma unroll
        for (int kk = 0; kk < 16; ++kk) {
            float a[4], b[4];
#pragma unroll
            for (int i = 0; i < 4; ++i) a[i] = As[kk][ty * 4 + i];
#pragma unroll
            for (int j = 0; j < 4; ++j) b[j] = Bs[kk][tx * 4 + j];
#pragma unroll
            for (int i = 0; i < 4; ++i)
#pragma unroll
                for (int j = 0; j < 4; ++j) acc[i][j] += a[i] * b[j];
        }
        __syncthreads();
    }
#pragma unroll
    for (int i = 0; i < 4; ++i)
#pragma unroll
        for (int j = 0; j < 4; ++j)
            C[(size_t)(m0 + ty * 4 + i) * N + n0 + tx * 4 + j] = acc[i][j];
}

// ---------------------------------------------------------------------------
// T = X @ Wgk1  (K=2048, N=16). Block = 16 rows x 16 cols.
// ---------------------------------------------------------------------------
__global__ __launch_bounds__(256) void gemm_n16(const float* __restrict__ X,
                                                const float* __restrict__ W,
                                                float* __restrict__ T, int K) {
    const int tid = threadIdx.x;
    const int jj = tid & 15;
    const int mm = tid >> 4;
    const size_t m = (size_t)blockIdx.x * 16 + mm;
    float acc = 0.f;
#pragma unroll 8
    for (int kk = 0; kk < K; ++kk) acc += X[m * K + kk] * W[kk * 16 + jj];
    T[m * 16 + jj] = acc;
}

// ---------------------------------------------------------------------------
// gk = log_sigmoid(T @ Wgk2 + bgk2) / 16. One thread per output (M*1024).
// ---------------------------------------------------------------------------
__global__ __launch_bounds__(256) void gk_act(const float* __restrict__ T,
                                              const float* __restrict__ W2,
                                              const float* __restrict__ b2,
                                              float* __restrict__ gk) {
    const int idx = blockIdx.x * 256 + threadIdx.x;
    const int n = idx & 1023;
    const int m = idx >> 10;
    float acc = b2[n];
#pragma unroll
    for (int j = 0; j < 16; ++j) acc += T[m * 16 + j] * W2[j * 1024 + n];
    // numerically stable log_sigmoid
    float ls = (acc < 0.f) ? (acc - log1pf(expf(acc))) : (-log1pf(expf(-acc)));
    gk[idx] = ls * 0.0625f;  // / GATE_NORMALIZER
}

// ---------------------------------------------------------------------------
// Gate prep: per (b,h,chunk,d) chain of 64 timesteps.
//   gc = cumsum(gk);  q <- q*exp(gc)*scale;  k <- k*exp(-gc);
//   glexp = exp(gc_last).     (k_dec = k_g * exp(g_last) -- folded into GLA.)
// idx = ((b*H+h)*NCHUNK + chunk)*DK + d
// ---------------------------------------------------------------------------
__global__ __launch_bounds__(256) void gate_prep(float* __restrict__ q,
                                                 float* __restrict__ k,
                                                 const float* __restrict__ gk,
                                                 float* __restrict__ glexp) {
    const int idx = blockIdx.x * 256 + threadIdx.x;
    const int d = idx & 255;
    const int chunk = (idx >> 8) & 31;
    const int h = (idx >> 13) & 3;
    const int b = idx >> 15;
    const size_t col = h * 256 + d;
    const size_t rowbase = (size_t)b * S_ + chunk * 64;
    const float scale = 0.0625f;  // DK^-0.5
    float gc = 0.f;
    for (int t = 0; t < 64; ++t) {
        size_t off = (rowbase + t) * (size_t)KD_ + col;
        gc += gk[off];
        q[off] = q[off] * expf(gc) * scale;
        k[off] = k[off] * expf(-gc);
    }
    glexp[idx] = expf(gc);
}

// ---------------------------------------------------------------------------
// GLA recurrence. Block = (b, h, ev-slice of 32). 128 blocks, 256 threads.
// State slice [256][32] persistent in LDS across the 32 sequential chunks.
// ---------------------------------------------------------------------------
#define EV 32
__global__ __launch_bounds__(256) void gla_kernel(const float* __restrict__ qg,
                                                  const float* __restrict__ kg,
                                                  const float* __restrict__ v,
                                                  const float* __restrict__ glexp,
                                                  float* __restrict__ o) {
    const int blk = blockIdx.x;
    const int sl = blk & 15;
    const int h = (blk >> 4) & 3;
    const int b = blk >> 6;
    const int ev0 = sl * EV;
    const int tid = threadIdx.x;
    const int bh = b * H_ + h;

    __shared__ float Ssh[256][EV];   // 32 KB state slice
    __shared__ float Ash[64][65];    // masked A
    __shared__ float qs[64][65];
    __shared__ float ks[64][65];
    __shared__ float vs[64][EV + 1];

    for (int i = tid; i < 256 * EV; i += 256) Ssh[i / EV][i % EV] = 0.f;
    __syncthreads();

    const size_t qk_base = (size_t)b * S_ * KD_ + h * 256;
    const size_t v_base = (size_t)b * S_ * VD_ + h * 512 + ev0;

    for (int chunk = 0; chunk < NCHUNK_; ++chunk) {
        const int s0 = chunk * 64;

        // ---- Phase 1: A = qg . kg^T over Dk (4 tiles of 64) ----
        float a_acc[16];
#pragma unroll
        for (int i = 0; i < 16; ++i) a_acc[i] = 0.f;
        const int jA = (tid & 15) * 4;
        const int iA = (tid >> 4) * 4;
        for (int dt = 0; dt < 4; ++dt) {
            __syncthreads();
            {
                const int c = tid & 63, rb = tid >> 6;
#pragma unroll
                for (int p = 0; p < 16; ++p) {
                    int r = rb + p * 4;
                    size_t off = qk_base + (size_t)(s0 + r) * KD_ + dt * 64 + c;
                    qs[r][c] = qg[off];
                    ks[r][c] = kg[off];
                }
            }
            __syncthreads();
            for (int dd = 0; dd < 64; ++dd) {
                float av[4], bv[4];
#pragma unroll
                for (int i = 0; i < 4; ++i) av[i] = qs[iA + i][dd];
#pragma unroll
                for (int j = 0; j < 4; ++j) bv[j] = ks[jA + j][dd];
#pragma unroll
                for (int i = 0; i < 4; ++i)
#pragma unroll
                    for (int j = 0; j < 4; ++j) a_acc[i * 4 + j] += av[i] * bv[j];
            }
        }
        __syncthreads();
        // write A with causal mask
#pragma unroll
        for (int i = 0; i < 4; ++i)
#pragma unroll
            for (int j = 0; j < 4; ++j)
                Ash[iA + i][jA + j] = (jA + j <= iA + i) ? a_acc[i * 4 + j] : 0.f;
        // stage v slice [64][32]
        {
            const int c = tid & 31, r0 = tid >> 5;
#pragma unroll
            for (int p = 0; p < 8; ++p) {
                int r = r0 + p * 8;
                vs[r][c] = v[v_base + (size_t)(s0 + r) * VD_ + c];
            }
        }
        __syncthreads();

        // ---- Phase 2: o = A @ v  +  qg @ S ----
        const int eo = (tid & 7) * 4;
        const int io = (tid >> 3) * 2;
        float o_acc[2][4] = {};
        for (int j = 0; j < 64; ++j) {
            float vv[4];
#pragma unroll
            for (int c = 0; c < 4; ++c) vv[c] = vs[j][eo + c];
#pragma unroll
            for (int i = 0; i < 2; ++i) {
                float a = Ash[io + i][j];
#pragma unroll
                for (int c = 0; c < 4; ++c) o_acc[i][c] += a * vv[c];
            }
        }
        for (int dt = 0; dt < 4; ++dt) {
            __syncthreads();
            {
                const int c = tid & 63, rb = tid >> 6;
#pragma unroll
                for (int p = 0; p < 16; ++p) {
                    int r = rb + p * 4;
                    qs[r][c] = qg[qk_base + (size_t)(s0 + r) * KD_ + dt * 64 + c];
                }
            }
            __syncthreads();
            for (int dd = 0; dd < 64; ++dd) {
                float sv[4];
#pragma unroll
                for (int c = 0; c < 4; ++c) sv[c] = Ssh[dt * 64 + dd][eo + c];
#pragma unroll
                for (int i = 0; i < 2; ++i) {
                    float qv = qs[io + i][dd];
#pragma unroll
                    for (int c = 0; c < 4; ++c) o_acc[i][c] += qv * sv[c];
                }
            }
        }
#pragma unroll
        for (int i = 0; i < 2; ++i)
#pragma unroll
            for (int c = 0; c < 4; ++c)
                o[v_base + (size_t)(s0 + io + i) * VD_ + eo + c] = o_acc[i][c];

        // ---- Phase 3: S = (S + kg^T v) * exp(g_last) ----
        for (int dt = 0; dt < 4; ++dt) {
            __syncthreads();
            {
                const int c = tid & 63, rb = tid >> 6;
#pragma unroll
                for (int p = 0; p < 16; ++p) {
                    int r = rb + p * 4;
                    ks[r][c] = kg[qk_base + (size_t)(s0 + r) * KD_ + dt * 64 + c];
                }
            }
            __syncthreads();
            const int es = (tid & 7) * 4;
            const int ds = (tid >> 3) * 2;
            float s_acc[2][4] = {};
            for (int t = 0; t < 64; ++t) {
                float vv[4];
#pragma unroll
                for (int c2 = 0; c2 < 4; ++c2) vv[c2] = vs[t][es + c2];
#pragma unroll
                for (int i = 0; i < 2; ++i) {
                    float kv = ks[t][ds + i];
#pragma unroll
                    for (int c2 = 0; c2 < 4; ++c2) s_acc[i][c2] += kv * vv[c2];
                }
            }
#pragma unroll
            for (int i = 0; i < 2; ++i) {
                int d = dt * 64 + ds + i;
                float ge = glexp[((size_t)(bh * NCHUNK_ + chunk)) * 256 + d];
#pragma unroll
                for (int c2 = 0; c2 < 4; ++c2)
                    Ssh[d][es + c2] = (Ssh[d][es + c2] + s_acc[i][c2]) * ge;
            }
        }
    }
}

// ---------------------------------------------------------------------------
// Post: RMS-norm over Dv=512 per (b,s,h), gated swish, in place on o.
// Block per (b,s); wave w handles head w.
// ---------------------------------------------------------------------------
__global__ __launch_bounds__(256) void postnorm(float* __restrict__ o,
                                                const float* __restrict__ g,
                                                const float* __restrict__ gnw) {
    const int row = blockIdx.x;
    const int wave = threadIdx.x >> 6;
    const int lane = threadIdx.x & 63;
    const size_t base = (size_t)row * VD_ + wave * 512;
    float x[8];
    float ss = 0.f;
#pragma unroll
    for (int j = 0; j < 8; ++j) {
        x[j] = o[base + lane + j * 64];
        ss += x[j] * x[j];
    }
#pragma unroll
    for (int off = 32; off; off >>= 1) ss += __shfl_xor(ss, off);
    const float inv = 1.0f / sqrtf(ss * (1.0f / 512.0f) + 1e-5f);
#pragma unroll
    for (int j = 0; j < 8; ++j) {
        int e = lane + j * 64;
        float gv = g[base + e];
        float sig = 1.0f / (1.0f + expf(-gv));
        o[base + e] = x[j] * inv * gnw[e] * (gv * sig);
    }
}

// ---------------------------------------------------------------------------
extern "C" void kernel_launch(void* const* d_in, const int* in_sizes, int n_in,
                              void* d_out, int out_size, void* d_ws, size_t ws_size,
                              hipStream_t stream) {
    const float* x    = (const float*)d_in[0];
    const float* Wq   = (const float*)d_in[1];
    const float* Wk   = (const float*)d_in[2];
    const float* Wv   = (const float*)d_in[3];
    const float* Wgk1 = (const float*)d_in[4];
    const float* Wgk2 = (const float*)d_in[5];
    const float* bgk2 = (const float*)d_in[6];
    const float* Wg   = (const float*)d_in[7];
    const float* gnw  = (const float*)d_in[8];
    const float* Wo   = (const float*)d_in[9];
    float* out = (float*)d_out;

    float* ws = (float*)d_ws;
    float* q   = ws;              // 4096*1024
    float* k   = q + 4194304;     // 4096*1024
    float* gk  = k + 4194304;     // 4096*1024
    float* v   = gk + 4194304;    // 4096*2048
    float* g   = v + 8388608;     // 4096*2048
    float* o   = g + 8388608;     // 4096*2048
    float* T   = o + 8388608;     // 4096*16
    float* gle = T + 65536;       // 65536

    dim3 blk(256);
    gemm64<<<dim3(KD_ / 64, M_ / 64), blk, 0, stream>>>(x, Wq, q, M_, KD_, HD_);
    gemm64<<<dim3(KD_ / 64, M_ / 64), blk, 0, stream>>>(x, Wk, k, M_, KD_, HD_);
    gemm64<<<dim3(VD_ / 64, M_ / 64), blk, 0, stream>>>(x, Wv, v, M_, VD_, HD_);
    gemm64<<<dim3(VD_ / 64, M_ / 64), blk, 0, stream>>>(x, Wg, g, M_, VD_, HD_);
    gemm_n16<<<M_ / 16, blk, 0, stream>>>(x, Wgk1, T, HD_);
    gk_act<<<(M_ * KD_) / 256, blk, 0, stream>>>(T, Wgk2, bgk2, gk);
    gate_prep<<<(B_ * H_ * NCHUNK_ * DK_) / 256, blk, 0, stream>>>(q, k, gk, gle);
    gla_kernel<<<B_ * H_ * (DV_ / EV), blk, 0, stream>>>(q, k, v, gle, o);
    postnorm<<<M_, blk, 0, stream>>>(o, g, gnw);
    gemm64<<<dim3(HD_ / 64, M_ / 64), blk, 0, stream>>>(o, Wo, out, M_, HD_, HD_);
}

// Round 2
// 2498.556 us; speedup vs baseline: 1.7515x; 1.7515x over previous
//
#include <hip/hip_runtime.h>
#include <hip/hip_bf16.h>

// Problem constants
#define B_   2
#define S_   2048
#define HD_  2048
#define H_   4
#define DK_  256
#define DV_  512
#define KD_  1024   // H_*DK_
#define VD_  2048   // H_*DV_
#define M_   4096   // B_*S_
#define NCHUNK_ 32
#define CHUNK_  64

typedef __attribute__((ext_vector_type(8))) short bf16x8;
typedef __attribute__((ext_vector_type(4))) float f32x4;
typedef __attribute__((ext_vector_type(4))) unsigned short us4;

__device__ __forceinline__ unsigned short f2bf(float f) {
    __hip_bfloat16 h = __float2bfloat16(f);
    return *reinterpret_cast<unsigned short*>(&h);
}

// ---------------------------------------------------------------------------
// bf16 MFMA GEMM: C[M][N](fp32) = A[M][K](fp32) @ B[K][N](fp32), converting
// to bf16 during LDS staging. Block tile 128x128, BK=32, 256 threads =
// 4 waves, each wave computes 64x64 as 4x4 grid of 16x16x32 MFMAs.
// M%128==0, N%128==0, K%32==0.
// ---------------------------------------------------------------------------
__global__ __launch_bounds__(256) void mfma_gemm(const float* __restrict__ A,
                                                 const float* __restrict__ B,
                                                 float* __restrict__ C,
                                                 int M, int N, int K) {
    // K-contiguous LDS, rows padded 32->40 bf16 (80 B: multiple of 16 B, and
    // 20-bank row stride -> only 2-way aliasing on ds_read_b128 fragments).
    __shared__ unsigned short As[128][40];  // [m][k]
    __shared__ unsigned short Bs[128][40];  // [n][k]  (B transposed in LDS)

    const int t = threadIdx.x;
    const int m0 = blockIdx.y * 128;
    const int n0 = blockIdx.x * 128;
    const int wave = t >> 6, lane = t & 63;
    const int quad = lane >> 4, l16 = lane & 15;
    const int wm = (wave >> 1) * 64, wn = (wave & 1) * 64;

    f32x4 acc[4][4] = {};

    for (int k0 = 0; k0 < K; k0 += 32) {
        __syncthreads();
        // Stage A: 128 rows x 32 k (fp32 -> bf16). 1024 float4, 4/thread.
#pragma unroll
        for (int p = 0; p < 4; ++p) {
            int q = t + p * 256;
            int row = q >> 3, c4 = q & 7;
            float4 a = *(const float4*)&A[(size_t)(m0 + row) * K + k0 + c4 * 4];
            us4 w; w.x = f2bf(a.x); w.y = f2bf(a.y); w.z = f2bf(a.z); w.w = f2bf(a.w);
            *(us4*)&As[row][c4 * 4] = w;
        }
        // Stage B transposed: read B[k][n] coalesced over n, write Bs[n][k].
#pragma unroll
        for (int p = 0; p < 4; ++p) {
            int q = t + p * 256;
            int kk = q >> 5, n4 = q & 31;
            float4 b = *(const float4*)&B[(size_t)(k0 + kk) * N + n0 + n4 * 4];
            Bs[n4 * 4 + 0][kk] = f2bf(b.x);
            Bs[n4 * 4 + 1][kk] = f2bf(b.y);
            Bs[n4 * 4 + 2][kk] = f2bf(b.z);
            Bs[n4 * 4 + 3][kk] = f2bf(b.w);
        }
        __syncthreads();

        bf16x8 af[4], bf[4];
#pragma unroll
        for (int i = 0; i < 4; ++i)
            af[i] = *(const bf16x8*)&As[wm + i * 16 + l16][quad * 8];
#pragma unroll
        for (int j = 0; j < 4; ++j)
            bf[j] = *(const bf16x8*)&Bs[wn + j * 16 + l16][quad * 8];
#pragma unroll
        for (int i = 0; i < 4; ++i)
#pragma unroll
            for (int j = 0; j < 4; ++j)
                acc[i][j] = __builtin_amdgcn_mfma_f32_16x16x32_bf16(af[i], bf[j], acc[i][j], 0, 0, 0);
    }

    // Epilogue: C/D layout col=lane&15, row=quad*4+reg.
#pragma unroll
    for (int i = 0; i < 4; ++i)
#pragma unroll
        for (int j = 0; j < 4; ++j)
#pragma unroll
            for (int r = 0; r < 4; ++r)
                C[(size_t)(m0 + wm + i * 16 + quad * 4 + r) * N + n0 + wn + j * 16 + l16] = acc[i][j][r];
}

// ---------------------------------------------------------------------------
// T = X @ Wgk1  (K=2048, N=16). Block = 16 rows x 16 cols.
// ---------------------------------------------------------------------------
__global__ __launch_bounds__(256) void gemm_n16(const float* __restrict__ X,
                                                const float* __restrict__ W,
                                                float* __restrict__ T, int K) {
    const int tid = threadIdx.x;
    const int jj = tid & 15;
    const int mm = tid >> 4;
    const size_t m = (size_t)blockIdx.x * 16 + mm;
    float acc = 0.f;
#pragma unroll 8
    for (int kk = 0; kk < K; ++kk) acc += X[m * K + kk] * W[kk * 16 + jj];
    T[m * 16 + jj] = acc;
}

// ---------------------------------------------------------------------------
// gk = log_sigmoid(T @ Wgk2 + bgk2) / 16. One thread per output (M*1024).
// ---------------------------------------------------------------------------
__global__ __launch_bounds__(256) void gk_act(const float* __restrict__ T,
                                              const float* __restrict__ W2,
                                              const float* __restrict__ b2,
                                              float* __restrict__ gk) {
    const int idx = blockIdx.x * 256 + threadIdx.x;
    const int n = idx & 1023;
    const int m = idx >> 10;
    float acc = b2[n];
#pragma unroll
    for (int j = 0; j < 16; ++j) acc += T[m * 16 + j] * W2[j * 1024 + n];
    float ls = (acc < 0.f) ? (acc - log1pf(expf(acc))) : (-log1pf(expf(-acc)));
    gk[idx] = ls * 0.0625f;  // / GATE_NORMALIZER
}

// ---------------------------------------------------------------------------
// Gate prep: per (b,h,chunk,d) chain of 64 timesteps.
// ---------------------------------------------------------------------------
__global__ __launch_bounds__(256) void gate_prep(float* __restrict__ q,
                                                 float* __restrict__ k,
                                                 const float* __restrict__ gk,
                                                 float* __restrict__ glexp) {
    const int idx = blockIdx.x * 256 + threadIdx.x;
    const int d = idx & 255;
    const int chunk = (idx >> 8) & 31;
    const int h = (idx >> 13) & 3;
    const int b = idx >> 15;
    const size_t col = h * 256 + d;
    const size_t rowbase = (size_t)b * S_ + chunk * 64;
    const float scale = 0.0625f;  // DK^-0.5
    float gc = 0.f;
    for (int t = 0; t < 64; ++t) {
        size_t off = (rowbase + t) * (size_t)KD_ + col;
        gc += gk[off];
        q[off] = q[off] * expf(gc) * scale;
        k[off] = k[off] * expf(-gc);
    }
    glexp[idx] = expf(gc);
}

// ---------------------------------------------------------------------------
// GLA recurrence. Block = (b, h, ev-slice of 32). 128 blocks, 256 threads.
// ---------------------------------------------------------------------------
#define EV 32
__global__ __launch_bounds__(256) void gla_kernel(const float* __restrict__ qg,
                                                  const float* __restrict__ kg,
                                                  const float* __restrict__ v,
                                                  const float* __restrict__ glexp,
                                                  float* __restrict__ o) {
    const int blk = blockIdx.x;
    const int sl = blk & 15;
    const int h = (blk >> 4) & 3;
    const int b = blk >> 6;
    const int ev0 = sl * EV;
    const int tid = threadIdx.x;
    const int bh = b * H_ + h;

    __shared__ float Ssh[256][EV];   // 32 KB state slice
    __shared__ float Ash[64][65];    // masked A
    __shared__ float qs[64][65];
    __shared__ float ks[64][65];
    __shared__ float vs[64][EV + 1];

    for (int i = tid; i < 256 * EV; i += 256) Ssh[i / EV][i % EV] = 0.f;
    __syncthreads();

    const size_t qk_base = (size_t)b * S_ * KD_ + h * 256;
    const size_t v_base = (size_t)b * S_ * VD_ + h * 512 + ev0;

    for (int chunk = 0; chunk < NCHUNK_; ++chunk) {
        const int s0 = chunk * 64;

        // ---- Phase 1: A = qg . kg^T over Dk (4 tiles of 64) ----
        float a_acc[16];
#pragma unroll
        for (int i = 0; i < 16; ++i) a_acc[i] = 0.f;
        const int jA = (tid & 15) * 4;
        const int iA = (tid >> 4) * 4;
        for (int dt = 0; dt < 4; ++dt) {
            __syncthreads();
            {
                const int c = tid & 63, rb = tid >> 6;
#pragma unroll
                for (int p = 0; p < 16; ++p) {
                    int r = rb + p * 4;
                    size_t off = qk_base + (size_t)(s0 + r) * KD_ + dt * 64 + c;
                    qs[r][c] = qg[off];
                    ks[r][c] = kg[off];
                }
            }
            __syncthreads();
            for (int dd = 0; dd < 64; ++dd) {
                float av[4], bv[4];
#pragma unroll
                for (int i = 0; i < 4; ++i) av[i] = qs[iA + i][dd];
#pragma unroll
                for (int j = 0; j < 4; ++j) bv[j] = ks[jA + j][dd];
#pragma unroll
                for (int i = 0; i < 4; ++i)
#pragma unroll
                    for (int j = 0; j < 4; ++j) a_acc[i * 4 + j] += av[i] * bv[j];
            }
        }
        __syncthreads();
#pragma unroll
        for (int i = 0; i < 4; ++i)
#pragma unroll
            for (int j = 0; j < 4; ++j)
                Ash[iA + i][jA + j] = (jA + j <= iA + i) ? a_acc[i * 4 + j] : 0.f;
        {
            const int c = tid & 31, r0 = tid >> 5;
#pragma unroll
            for (int p = 0; p < 8; ++p) {
                int r = r0 + p * 8;
                vs[r][c] = v[v_base + (size_t)(s0 + r) * VD_ + c];
            }
        }
        __syncthreads();

        // ---- Phase 2: o = A @ v  +  qg @ S ----
        const int eo = (tid & 7) * 4;
        const int io = (tid >> 3) * 2;
        float o_acc[2][4] = {};
        for (int j = 0; j < 64; ++j) {
            float vv[4];
#pragma unroll
            for (int c = 0; c < 4; ++c) vv[c] = vs[j][eo + c];
#pragma unroll
            for (int i = 0; i < 2; ++i) {
                float a = Ash[io + i][j];
#pragma unroll
                for (int c = 0; c < 4; ++c) o_acc[i][c] += a * vv[c];
            }
        }
        for (int dt = 0; dt < 4; ++dt) {
            __syncthreads();
            {
                const int c = tid & 63, rb = tid >> 6;
#pragma unroll
                for (int p = 0; p < 16; ++p) {
                    int r = rb + p * 4;
                    qs[r][c] = qg[qk_base + (size_t)(s0 + r) * KD_ + dt * 64 + c];
                }
            }
            __syncthreads();
            for (int dd = 0; dd < 64; ++dd) {
                float sv[4];
#pragma unroll
                for (int c = 0; c < 4; ++c) sv[c] = Ssh[dt * 64 + dd][eo + c];
#pragma unroll
                for (int i = 0; i < 2; ++i) {
                    float qv = qs[io + i][dd];
#pragma unroll
                    for (int c = 0; c < 4; ++c) o_acc[i][c] += qv * sv[c];
                }
            }
        }
#pragma unroll
        for (int i = 0; i < 2; ++i)
#pragma unroll
            for (int c = 0; c < 4; ++c)
                o[v_base + (size_t)(s0 + io + i) * VD_ + eo + c] = o_acc[i][c];

        // ---- Phase 3: S = (S + kg^T v) * exp(g_last) ----
        for (int dt = 0; dt < 4; ++dt) {
            __syncthreads();
            {
                const int c = tid & 63, rb = tid >> 6;
#pragma unroll
                for (int p = 0; p < 16; ++p) {
                    int r = rb + p * 4;
                    ks[r][c] = kg[qk_base + (size_t)(s0 + r) * KD_ + dt * 64 + c];
                }
            }
            __syncthreads();
            const int es = (tid & 7) * 4;
            const int ds = (tid >> 3) * 2;
            float s_acc[2][4] = {};
            for (int t = 0; t < 64; ++t) {
                float vv[4];
#pragma unroll
                for (int c2 = 0; c2 < 4; ++c2) vv[c2] = vs[t][es + c2];
#pragma unroll
                for (int i = 0; i < 2; ++i) {
                    float kv = ks[t][ds + i];
#pragma unroll
                    for (int c2 = 0; c2 < 4; ++c2) s_acc[i][c2] += kv * vv[c2];
                }
            }
#pragma unroll
            for (int i = 0; i < 2; ++i) {
                int d = dt * 64 + ds + i;
                float ge = glexp[((size_t)(bh * NCHUNK_ + chunk)) * 256 + d];
#pragma unroll
                for (int c2 = 0; c2 < 4; ++c2)
                    Ssh[d][es + c2] = (Ssh[d][es + c2] + s_acc[i][c2]) * ge;
            }
        }
    }
}

// ---------------------------------------------------------------------------
// Post: RMS-norm over Dv=512 per (b,s,h), gated swish, in place on o.
// ---------------------------------------------------------------------------
__global__ __launch_bounds__(256) void postnorm(float* __restrict__ o,
                                                const float* __restrict__ g,
                                                const float* __restrict__ gnw) {
    const int row = blockIdx.x;
    const int wave = threadIdx.x >> 6;
    const int lane = threadIdx.x & 63;
    const size_t base = (size_t)row * VD_ + wave * 512;
    float x[8];
    float ss = 0.f;
#pragma unroll
    for (int j = 0; j < 8; ++j) {
        x[j] = o[base + lane + j * 64];
        ss += x[j] * x[j];
    }
#pragma unroll
    for (int off = 32; off; off >>= 1) ss += __shfl_xor(ss, off);
    const float inv = 1.0f / sqrtf(ss * (1.0f / 512.0f) + 1e-5f);
#pragma unroll
    for (int j = 0; j < 8; ++j) {
        int e = lane + j * 64;
        float gv = g[base + e];
        float sig = 1.0f / (1.0f + expf(-gv));
        o[base + e] = x[j] * inv * gnw[e] * (gv * sig);
    }
}

// ---------------------------------------------------------------------------
extern "C" void kernel_launch(void* const* d_in, const int* in_sizes, int n_in,
                              void* d_out, int out_size, void* d_ws, size_t ws_size,
                              hipStream_t stream) {
    const float* x    = (const float*)d_in[0];
    const float* Wq   = (const float*)d_in[1];
    const float* Wk   = (const float*)d_in[2];
    const float* Wv   = (const float*)d_in[3];
    const float* Wgk1 = (const float*)d_in[4];
    const float* Wgk2 = (const float*)d_in[5];
    const float* bgk2 = (const float*)d_in[6];
    const float* Wg   = (const float*)d_in[7];
    const float* gnw  = (const float*)d_in[8];
    const float* Wo   = (const float*)d_in[9];
    float* out = (float*)d_out;

    float* ws = (float*)d_ws;
    float* q   = ws;              // 4096*1024
    float* k   = q + 4194304;     // 4096*1024
    float* gk  = k + 4194304;     // 4096*1024
    float* v   = gk + 4194304;    // 4096*2048
    float* g   = v + 8388608;     // 4096*2048
    float* o   = g + 8388608;     // 4096*2048
    float* T   = o + 8388608;     // 4096*16
    float* gle = T + 65536;       // 65536

    dim3 blk(256);
    mfma_gemm<<<dim3(KD_ / 128, M_ / 128), blk, 0, stream>>>(x, Wq, q, M_, KD_, HD_);
    mfma_gemm<<<dim3(KD_ / 128, M_ / 128), blk, 0, stream>>>(x, Wk, k, M_, KD_, HD_);
    mfma_gemm<<<dim3(VD_ / 128, M_ / 128), blk, 0, stream>>>(x, Wv, v, M_, VD_, HD_);
    mfma_gemm<<<dim3(VD_ / 128, M_ / 128), blk, 0, stream>>>(x, Wg, g, M_, VD_, HD_);
    gemm_n16<<<M_ / 16, blk, 0, stream>>>(x, Wgk1, T, HD_);
    gk_act<<<(M_ * KD_) / 256, blk, 0, stream>>>(T, Wgk2, bgk2, gk);
    gate_prep<<<(B_ * H_ * NCHUNK_ * DK_) / 256, blk, 0, stream>>>(q, k, gk, gle);
    gla_kernel<<<B_ * H_ * (DV_ / EV), blk, 0, stream>>>(q, k, v, gle, o);
    postnorm<<<M_, blk, 0, stream>>>(o, g, gnw);
    mfma_gemm<<<dim3(HD_ / 128, M_ / 128), blk, 0, stream>>>(o, Wo, out, M_, HD_, HD_);
}

// Round 3
// 1200.216 us; speedup vs baseline: 3.6461x; 2.0818x over previous
//
#include <hip/hip_runtime.h>
#include <hip/hip_bf16.h>

// Problem constants
#define B_   2
#define S_   2048
#define HD_  2048
#define H_   4
#define DK_  256
#define DV_  512
#define KD_  1024   // H_*DK_
#define VD_  2048   // H_*DV_
#define M_   4096   // B_*S_
#define NCHUNK_ 32
#define CHUNK_  64

typedef __attribute__((ext_vector_type(8))) short bf16x8;
typedef __attribute__((ext_vector_type(4))) float f32x4;
typedef __attribute__((ext_vector_type(4))) unsigned short us4;
typedef __attribute__((ext_vector_type(8))) unsigned short us8;

__device__ __forceinline__ unsigned short f2bf(float f) {
    __hip_bfloat16 h = __float2bfloat16(f);
    return *reinterpret_cast<unsigned short*>(&h);
}
__device__ __forceinline__ float bf2f(unsigned short u) {
    unsigned int x = ((unsigned int)u) << 16;
    return *reinterpret_cast<float*>(&x);
}

// ---------------------------------------------------------------------------
// bf16 MFMA GEMM: C[M][N](fp32) = A[M][K](fp32) @ B[K][N](fp32).
// Block tile 128x128, BK=32, 4 waves each 64x64 of 16x16x32 MFMAs.
// ---------------------------------------------------------------------------
__global__ __launch_bounds__(256) void mfma_gemm(const float* __restrict__ A,
                                                 const float* __restrict__ B,
                                                 float* __restrict__ C,
                                                 int M, int N, int K) {
    __shared__ unsigned short As[128][40];  // [m][k]
    __shared__ unsigned short Bs[128][40];  // [n][k]

    const int t = threadIdx.x;
    const int m0 = blockIdx.y * 128;
    const int n0 = blockIdx.x * 128;
    const int wave = t >> 6, lane = t & 63;
    const int quad = lane >> 4, l16 = lane & 15;
    const int wm = (wave >> 1) * 64, wn = (wave & 1) * 64;

    f32x4 acc[4][4] = {};

    for (int k0 = 0; k0 < K; k0 += 32) {
        __syncthreads();
#pragma unroll
        for (int p = 0; p < 4; ++p) {
            int q = t + p * 256;
            int row = q >> 3, c4 = q & 7;
            float4 a = *(const float4*)&A[(size_t)(m0 + row) * K + k0 + c4 * 4];
            us4 w; w.x = f2bf(a.x); w.y = f2bf(a.y); w.z = f2bf(a.z); w.w = f2bf(a.w);
            *(us4*)&As[row][c4 * 4] = w;
        }
#pragma unroll
        for (int p = 0; p < 4; ++p) {
            int q = t + p * 256;
            int kk = q >> 5, n4 = q & 31;
            float4 b = *(const float4*)&B[(size_t)(k0 + kk) * N + n0 + n4 * 4];
            Bs[n4 * 4 + 0][kk] = f2bf(b.x);
            Bs[n4 * 4 + 1][kk] = f2bf(b.y);
            Bs[n4 * 4 + 2][kk] = f2bf(b.z);
            Bs[n4 * 4 + 3][kk] = f2bf(b.w);
        }
        __syncthreads();

        bf16x8 af[4], bfr[4];
#pragma unroll
        for (int i = 0; i < 4; ++i)
            af[i] = *(const bf16x8*)&As[wm + i * 16 + l16][quad * 8];
#pragma unroll
        for (int j = 0; j < 4; ++j)
            bfr[j] = *(const bf16x8*)&Bs[wn + j * 16 + l16][quad * 8];
#pragma unroll
        for (int i = 0; i < 4; ++i)
#pragma unroll
            for (int j = 0; j < 4; ++j)
                acc[i][j] = __builtin_amdgcn_mfma_f32_16x16x32_bf16(af[i], bfr[j], acc[i][j], 0, 0, 0);
    }

#pragma unroll
    for (int i = 0; i < 4; ++i)
#pragma unroll
        for (int j = 0; j < 4; ++j)
#pragma unroll
            for (int r = 0; r < 4; ++r)
                C[(size_t)(m0 + wm + i * 16 + quad * 4 + r) * N + n0 + wn + j * 16 + l16] = acc[i][j][r];
}

// ---------------------------------------------------------------------------
// T = X @ Wgk1  (K=2048, N=16).
// ---------------------------------------------------------------------------
__global__ __launch_bounds__(256) void gemm_n16(const float* __restrict__ X,
                                                const float* __restrict__ W,
                                                float* __restrict__ T, int K) {
    const int tid = threadIdx.x;
    const int jj = tid & 15;
    const int mm = tid >> 4;
    const size_t m = (size_t)blockIdx.x * 16 + mm;
    float acc = 0.f;
#pragma unroll 8
    for (int kk = 0; kk < K; ++kk) acc += X[m * K + kk] * W[kk * 16 + jj];
    T[m * 16 + jj] = acc;
}

// ---------------------------------------------------------------------------
// gk = log_sigmoid(T @ Wgk2 + bgk2) / 16.
// ---------------------------------------------------------------------------
__global__ __launch_bounds__(256) void gk_act(const float* __restrict__ T,
                                              const float* __restrict__ W2,
                                              const float* __restrict__ b2,
                                              float* __restrict__ gk) {
    const int idx = blockIdx.x * 256 + threadIdx.x;
    const int n = idx & 1023;
    const int m = idx >> 10;
    float acc = b2[n];
#pragma unroll
    for (int j = 0; j < 16; ++j) acc += T[m * 16 + j] * W2[j * 1024 + n];
    float ls = (acc < 0.f) ? (acc - log1pf(expf(acc))) : (-log1pf(expf(-acc)));
    gk[idx] = ls * 0.0625f;  // / GATE_NORMALIZER
}

// ---------------------------------------------------------------------------
// Gate prep: q <- q*exp(gc)*scale; k <- k*exp(-gc); glexp = exp(gc_last).
// glexp layout: [(bh*32+chunk)*256 + d]
// ---------------------------------------------------------------------------
__global__ __launch_bounds__(256) void gate_prep(float* __restrict__ q,
                                                 float* __restrict__ k,
                                                 const float* __restrict__ gk,
                                                 float* __restrict__ glexp) {
    const int idx = blockIdx.x * 256 + threadIdx.x;
    const int d = idx & 255;
    const int chunk = (idx >> 8) & 31;
    const int h = (idx >> 13) & 3;
    const int b = idx >> 15;
    const size_t col = h * 256 + d;
    const size_t rowbase = (size_t)b * S_ + chunk * 64;
    const float scale = 0.0625f;  // DK^-0.5
    float gc = 0.f;
    for (int t = 0; t < 64; ++t) {
        size_t off = (rowbase + t) * (size_t)KD_ + col;
        gc += gk[off];
        q[off] = q[off] * expf(gc) * scale;
        k[off] = k[off] * expf(-gc);
    }
    glexp[idx] = expf(gc);
}

// ---------------------------------------------------------------------------
// Pass A: Dt[bhc][e][d] = sum_t v[t,e]*k_g[t,d]  (bf16 out).
// Per (bh,chunk): M=512(e), N=256(d), K=64(t). Tile 128x128, 2 K-steps of 32.
// grid(x=2 dn, y=4 em, z=256 bhc)
// ---------------------------------------------------------------------------
__global__ __launch_bounds__(256) void pass_a(const float* __restrict__ kg,
                                              const float* __restrict__ v,
                                              unsigned short* __restrict__ Dt) {
    __shared__ unsigned short As[128][40];  // [e][t]
    __shared__ unsigned short Bs[128][40];  // [d][t]

    const int t = threadIdx.x;
    const int bhc = blockIdx.z;
    const int chunk = bhc & 31, bh = bhc >> 5;
    const int h = bh & 3, b = bh >> 2;
    const int s0 = chunk * 64;
    const int e0 = blockIdx.y * 128;
    const int d0 = blockIdx.x * 128;
    const int wave = t >> 6, lane = t & 63;
    const int quad = lane >> 4, l16 = lane & 15;
    const int wm = (wave >> 1) * 64, wn = (wave & 1) * 64;

    f32x4 acc[4][4] = {};

    for (int k0 = 0; k0 < 64; k0 += 32) {
        __syncthreads();
        // A = v^T: read v rows (coalesced over e), scatter [e][t]
#pragma unroll
        for (int p = 0; p < 4; ++p) {
            int q = t + p * 256;
            int kk = q >> 5, n4 = q & 31;
            float4 a = *(const float4*)&v[((size_t)b * S_ + s0 + k0 + kk) * VD_ + h * DV_ + e0 + n4 * 4];
            As[n4 * 4 + 0][kk] = f2bf(a.x);
            As[n4 * 4 + 1][kk] = f2bf(a.y);
            As[n4 * 4 + 2][kk] = f2bf(a.z);
            As[n4 * 4 + 3][kk] = f2bf(a.w);
        }
        // B = k_g^T: read k_g rows, scatter [d][t]
#pragma unroll
        for (int p = 0; p < 4; ++p) {
            int q = t + p * 256;
            int kk = q >> 5, n4 = q & 31;
            float4 bb = *(const float4*)&kg[((size_t)b * S_ + s0 + k0 + kk) * KD_ + h * DK_ + d0 + n4 * 4];
            Bs[n4 * 4 + 0][kk] = f2bf(bb.x);
            Bs[n4 * 4 + 1][kk] = f2bf(bb.y);
            Bs[n4 * 4 + 2][kk] = f2bf(bb.z);
            Bs[n4 * 4 + 3][kk] = f2bf(bb.w);
        }
        __syncthreads();

        bf16x8 af[4], bfr[4];
#pragma unroll
        for (int i = 0; i < 4; ++i)
            af[i] = *(const bf16x8*)&As[wm + i * 16 + l16][quad * 8];
#pragma unroll
        for (int j = 0; j < 4; ++j)
            bfr[j] = *(const bf16x8*)&Bs[wn + j * 16 + l16][quad * 8];
#pragma unroll
        for (int i = 0; i < 4; ++i)
#pragma unroll
            for (int j = 0; j < 4; ++j)
                acc[i][j] = __builtin_amdgcn_mfma_f32_16x16x32_bf16(af[i], bfr[j], acc[i][j], 0, 0, 0);
    }

#pragma unroll
    for (int i = 0; i < 4; ++i)
#pragma unroll
        for (int j = 0; j < 4; ++j)
#pragma unroll
            for (int r = 0; r < 4; ++r) {
                size_t e = e0 + wm + i * 16 + quad * 4 + r;
                size_t d = d0 + wn + j * 16 + l16;
                Dt[((size_t)bhc * 512 + e) * 256 + d] = f2bf(acc[i][j][r]);
            }
}

// ---------------------------------------------------------------------------
// Pass B: diagonal scan. Thread owns (bh, e, 8 d's); loops 32 chunks:
//   write entering S (bf16), then S = (S + D)*E[d].
// grid 512 x 256.
// ---------------------------------------------------------------------------
__global__ __launch_bounds__(256) void pass_b(const unsigned short* __restrict__ Dt,
                                              const float* __restrict__ gle,
                                              unsigned short* __restrict__ St) {
    const int gid = blockIdx.x * 256 + threadIdx.x;
    const int bh = gid >> 14;
    const int rem = gid & 16383;
    const int e = rem >> 5;
    const int d8 = (rem & 31) * 8;

    float S[8];
#pragma unroll
    for (int i = 0; i < 8; ++i) S[i] = 0.f;

    for (int n = 0; n < NCHUNK_; ++n) {
        const size_t row = (((size_t)(bh * 32 + n)) * 512 + e) * 256 + d8;
        us8 w;
#pragma unroll
        for (int i = 0; i < 8; ++i) w[i] = f2bf(S[i]);
        *(us8*)&St[row] = w;
        us8 dv = *(const us8*)&Dt[row];
        float4 e0 = *(const float4*)&gle[(size_t)(bh * 32 + n) * 256 + d8];
        float4 e1 = *(const float4*)&gle[(size_t)(bh * 32 + n) * 256 + d8 + 4];
        float E[8] = {e0.x, e0.y, e0.z, e0.w, e1.x, e1.y, e1.z, e1.w};
#pragma unroll
        for (int i = 0; i < 8; ++i) S[i] = (S[i] + bf2f(dv[i])) * E[i];
    }
}

// ---------------------------------------------------------------------------
// Pass C1: A_s[bhc][t][j] = tril(q_g k_g^T)  (64x64, K=256) -> bf16.
// grid 256 blocks; wave w covers j-slice w*16.
// ---------------------------------------------------------------------------
__global__ __launch_bounds__(256) void pass_c1(const float* __restrict__ qg,
                                               const float* __restrict__ kg,
                                               unsigned short* __restrict__ Asg) {
    __shared__ unsigned short Aq[64][40];
    __shared__ unsigned short Bk[64][40];

    const int t = threadIdx.x;
    const int bhc = blockIdx.x;
    const int chunk = bhc & 31, bh = bhc >> 5;
    const int h = bh & 3, b = bh >> 2;
    const int s0 = chunk * 64;
    const int wave = t >> 6, lane = t & 63;
    const int quad = lane >> 4, l16 = lane & 15;

    f32x4 acc[4] = {};

    for (int k0 = 0; k0 < 256; k0 += 32) {
        __syncthreads();
#pragma unroll
        for (int p = 0; p < 2; ++p) {
            int q = t + p * 256;
            int row = q >> 3, c4 = q & 7;
            size_t off = ((size_t)b * S_ + s0 + row) * KD_ + h * DK_ + k0 + c4 * 4;
            float4 a = *(const float4*)&qg[off];
            us4 w; w.x = f2bf(a.x); w.y = f2bf(a.y); w.z = f2bf(a.z); w.w = f2bf(a.w);
            *(us4*)&Aq[row][c4 * 4] = w;
            float4 bb = *(const float4*)&kg[off];
            us4 w2; w2.x = f2bf(bb.x); w2.y = f2bf(bb.y); w2.z = f2bf(bb.z); w2.w = f2bf(bb.w);
            *(us4*)&Bk[row][c4 * 4] = w2;
        }
        __syncthreads();

        bf16x8 bfr = *(const bf16x8*)&Bk[wave * 16 + l16][quad * 8];
#pragma unroll
        for (int i = 0; i < 4; ++i) {
            bf16x8 af = *(const bf16x8*)&Aq[i * 16 + l16][quad * 8];
            acc[i] = __builtin_amdgcn_mfma_f32_16x16x32_bf16(af, bfr, acc[i], 0, 0, 0);
        }
    }

    const int j = wave * 16 + l16;
#pragma unroll
    for (int i = 0; i < 4; ++i)
#pragma unroll
        for (int r = 0; r < 4; ++r) {
            int m = i * 16 + quad * 4 + r;
            float val = (j <= m) ? acc[i][r] : 0.f;
            Asg[(size_t)bhc * 4096 + m * 64 + j] = f2bf(val);
        }
}

// ---------------------------------------------------------------------------
// Pass C2: o[t][e] = sum_k [A_s | q_g][t][k] * [v ; S^T][k][e]   (K=320).
// grid(x=2 e-half, z=256 bhc). Wave w covers e-slice w*64 within the half.
// ---------------------------------------------------------------------------
__global__ __launch_bounds__(256) void pass_c2(const float* __restrict__ qg,
                                               const float* __restrict__ v,
                                               const unsigned short* __restrict__ Asg,
                                               const unsigned short* __restrict__ St,
                                               float* __restrict__ o) {
    __shared__ unsigned short At[64][40];   // [t][k]
    __shared__ unsigned short Bt[256][40];  // [e][k]

    const int t = threadIdx.x;
    const int bhc = blockIdx.z;
    const int chunk = bhc & 31, bh = bhc >> 5;
    const int h = bh & 3, b = bh >> 2;
    const int s0 = chunk * 64;
    const int eh = blockIdx.x * 256;  // e-half base within head
    const int wave = t >> 6, lane = t & 63;
    const int quad = lane >> 4, l16 = lane & 15;
    const int we = wave * 64;

    f32x4 acc[4][4] = {};

    for (int kk0 = 0; kk0 < 10; ++kk0) {
        __syncthreads();
        if (kk0 < 2) {
            // A from A_s (bf16 rows)
            {
                int row = t >> 2, c8 = t & 3;
                us8 w = *(const us8*)&Asg[(size_t)bhc * 4096 + row * 64 + kk0 * 32 + c8 * 8];
                *(us8*)&At[row][c8 * 8] = w;
            }
            // B from v (fp32, transpose-stage): k = t-dim
            const int t0 = kk0 * 32;
#pragma unroll
            for (int p = 0; p < 8; ++p) {
                int q = t + p * 256;
                int kk = q >> 6, e4 = q & 63;
                float4 bb = *(const float4*)&v[((size_t)b * S_ + s0 + t0 + kk) * VD_ + h * DV_ + eh + e4 * 4];
                Bt[e4 * 4 + 0][kk] = f2bf(bb.x);
                Bt[e4 * 4 + 1][kk] = f2bf(bb.y);
                Bt[e4 * 4 + 2][kk] = f2bf(bb.z);
                Bt[e4 * 4 + 3][kk] = f2bf(bb.w);
            }
        } else {
            const int d0 = (kk0 - 2) * 32;
            // A from q_g (fp32 rows)
#pragma unroll
            for (int p = 0; p < 2; ++p) {
                int q = t + p * 256;
                int row = q >> 3, c4 = q & 7;
                float4 a = *(const float4*)&qg[((size_t)b * S_ + s0 + row) * KD_ + h * DK_ + d0 + c4 * 4];
                us4 w; w.x = f2bf(a.x); w.y = f2bf(a.y); w.z = f2bf(a.z); w.w = f2bf(a.w);
                *(us4*)&At[row][c4 * 4] = w;
            }
            // B from S^T (bf16 rows)
#pragma unroll
            for (int p = 0; p < 4; ++p) {
                int q = t + p * 256;
                int row = q >> 2, c8 = q & 3;
                us8 w = *(const us8*)&St[(((size_t)bhc) * 512 + eh + row) * 256 + d0 + c8 * 8];
                *(us8*)&Bt[row][c8 * 8] = w;
            }
        }
        __syncthreads();

        bf16x8 af[4], bfr[4];
#pragma unroll
        for (int i = 0; i < 4; ++i)
            af[i] = *(const bf16x8*)&At[i * 16 + l16][quad * 8];
#pragma unroll
        for (int j = 0; j < 4; ++j)
            bfr[j] = *(const bf16x8*)&Bt[we + j * 16 + l16][quad * 8];
#pragma unroll
        for (int i = 0; i < 4; ++i)
#pragma unroll
            for (int j = 0; j < 4; ++j)
                acc[i][j] = __builtin_amdgcn_mfma_f32_16x16x32_bf16(af[i], bfr[j], acc[i][j], 0, 0, 0);
    }

#pragma unroll
    for (int i = 0; i < 4; ++i)
#pragma unroll
        for (int j = 0; j < 4; ++j)
#pragma unroll
            for (int r = 0; r < 4; ++r) {
                int m = i * 16 + quad * 4 + r;
                int e = eh + we + j * 16 + l16;
                o[((size_t)b * S_ + s0 + m) * VD_ + h * DV_ + e] = acc[i][j][r];
            }
}

// ---------------------------------------------------------------------------
// Post: RMS-norm over Dv=512 per (b,s,h), gated swish, in place on o.
// ---------------------------------------------------------------------------
__global__ __launch_bounds__(256) void postnorm(float* __restrict__ o,
                                                const float* __restrict__ g,
                                                const float* __restrict__ gnw) {
    const int row = blockIdx.x;
    const int wave = threadIdx.x >> 6;
    const int lane = threadIdx.x & 63;
    const size_t base = (size_t)row * VD_ + wave * 512;
    float x[8];
    float ss = 0.f;
#pragma unroll
    for (int j = 0; j < 8; ++j) {
        x[j] = o[base + lane + j * 64];
        ss += x[j] * x[j];
    }
#pragma unroll
    for (int off = 32; off; off >>= 1) ss += __shfl_xor(ss, off);
    const float inv = 1.0f / sqrtf(ss * (1.0f / 512.0f) + 1e-5f);
#pragma unroll
    for (int j = 0; j < 8; ++j) {
        int e = lane + j * 64;
        float gv = g[base + e];
        float sig = 1.0f / (1.0f + expf(-gv));
        o[base + e] = x[j] * inv * gnw[e] * (gv * sig);
    }
}

// ---------------------------------------------------------------------------
extern "C" void kernel_launch(void* const* d_in, const int* in_sizes, int n_in,
                              void* d_out, int out_size, void* d_ws, size_t ws_size,
                              hipStream_t stream) {
    const float* x    = (const float*)d_in[0];
    const float* Wq   = (const float*)d_in[1];
    const float* Wk   = (const float*)d_in[2];
    const float* Wv   = (const float*)d_in[3];
    const float* Wgk1 = (const float*)d_in[4];
    const float* Wgk2 = (const float*)d_in[5];
    const float* bgk2 = (const float*)d_in[6];
    const float* Wg   = (const float*)d_in[7];
    const float* gnw  = (const float*)d_in[8];
    const float* Wo   = (const float*)d_in[9];
    float* out = (float*)d_out;

    float* ws = (float*)d_ws;
    const size_t MB1 = 1048576;
    float* q   = ws;                    // 4M floats
    float* k   = ws + 4 * MB1;          // 4M
    float* gk  = ws + 8 * MB1;          // 4M (dead after gate_prep)
    float* v   = ws + 12 * MB1;         // 8M
    float* g   = ws + 20 * MB1;         // 8M (written AFTER pass_b)
    float* o   = ws + 28 * MB1;         // 8M (written in pass_c2)
    float* T   = ws + 36 * MB1;         // 65536
    float* gle = T + 65536;             // 65536
    float* Sf  = gle + 65536;           // 16M float-slots for S^T bf16
    unsigned short* Asg = (unsigned short*)gk;   // 1M bf16 over dead gk
    unsigned short* Dt  = (unsigned short*)g;    // 32M bf16 over g|o (dead until pass_b done)
    unsigned short* St  = (unsigned short*)Sf;   // 32M bf16

    dim3 blk(256);
    // projections (g's GEMM deferred until D^T is dead)
    mfma_gemm<<<dim3(KD_ / 128, M_ / 128), blk, 0, stream>>>(x, Wq, q, M_, KD_, HD_);
    mfma_gemm<<<dim3(KD_ / 128, M_ / 128), blk, 0, stream>>>(x, Wk, k, M_, KD_, HD_);
    mfma_gemm<<<dim3(VD_ / 128, M_ / 128), blk, 0, stream>>>(x, Wv, v, M_, VD_, HD_);
    gemm_n16<<<M_ / 16, blk, 0, stream>>>(x, Wgk1, T, HD_);
    gk_act<<<(M_ * KD_) / 256, blk, 0, stream>>>(T, Wgk2, bgk2, gk);
    gate_prep<<<(B_ * H_ * NCHUNK_ * DK_) / 256, blk, 0, stream>>>(q, k, gk, gle);
    // GLA passes
    pass_c1<<<256, blk, 0, stream>>>(q, k, Asg);
    pass_a<<<dim3(2, 4, 256), blk, 0, stream>>>(k, v, Dt);
    pass_b<<<512, blk, 0, stream>>>(Dt, gle, St);
    mfma_gemm<<<dim3(VD_ / 128, M_ / 128), blk, 0, stream>>>(x, Wg, g, M_, VD_, HD_);
    pass_c2<<<dim3(2, 1, 256), blk, 0, stream>>>(q, v, Asg, St, o);
    postnorm<<<M_, blk, 0, stream>>>(o, g, gnw);
    mfma_gemm<<<dim3(HD_ / 128, M_ / 128), blk, 0, stream>>>(o, Wo, out, M_, HD_, HD_);
}

// Round 6
// 614.742 us; speedup vs baseline: 7.1187x; 1.9524x over previous
//
#include <hip/hip_runtime.h>
#include <hip/hip_bf16.h>

// Problem constants
#define B_   2
#define S_   2048
#define HD_  2048
#define H_   4
#define DK_  256
#define DV_  512
#define KD_  1024   // H_*DK_
#define VD_  2048   // H_*DV_  (== value_dim; NOT multiplied by H_ again!)
#define M_   4096   // B_*S_
#define NCHUNK_ 32
#define CHUNK_  64

typedef __attribute__((ext_vector_type(8))) short bf16x8;
typedef __attribute__((ext_vector_type(4))) float f32x4;
typedef __attribute__((ext_vector_type(4))) unsigned short us4;
typedef __attribute__((ext_vector_type(8))) unsigned short us8;

__device__ __forceinline__ unsigned short f2bf(float f) {
    __hip_bfloat16 h = __float2bfloat16(f);
    return *reinterpret_cast<unsigned short*>(&h);
}
__device__ __forceinline__ float bf2f(unsigned short u) {
    unsigned int x = ((unsigned int)u) << 16;
    return *reinterpret_cast<float*>(&x);
}

// ---------------------------------------------------------------------------
// fp32 -> bf16 flat convert (x). One float4 per thread.
// ---------------------------------------------------------------------------
__global__ __launch_bounds__(256) void conv_bf16(const float* __restrict__ in,
                                                 unsigned short* __restrict__ out) {
    const int idx = blockIdx.x * 256 + threadIdx.x;
    float4 a = *(const float4*)&in[(size_t)idx * 4];
    us4 w; w.x = f2bf(a.x); w.y = f2bf(a.y); w.z = f2bf(a.z); w.w = f2bf(a.w);
    *(us4*)&out[(size_t)idx * 4] = w;
}

// ---------------------------------------------------------------------------
// Weight transpose: Wt[n][k](bf16) = W[k][n](fp32). 32x32 tiles via LDS.
// ---------------------------------------------------------------------------
__global__ __launch_bounds__(256) void tr_w(const float* __restrict__ W,
                                            unsigned short* __restrict__ Wt,
                                            int K, int N) {
    __shared__ float Ws[32][33];
    const int t = threadIdx.x;
    const int n0 = blockIdx.x * 32, k0 = blockIdx.y * 32;
    const int r = t >> 3, c4 = (t & 7) * 4;
    float4 a = *(const float4*)&W[(size_t)(k0 + r) * N + n0 + c4];
    Ws[r][c4 + 0] = a.x; Ws[r][c4 + 1] = a.y; Ws[r][c4 + 2] = a.z; Ws[r][c4 + 3] = a.w;
    __syncthreads();
    const int nr = t >> 3, kc4 = (t & 7) * 4;
    us4 w;
#pragma unroll
    for (int j = 0; j < 4; ++j) w[j] = f2bf(Ws[kc4 + j][nr]);
    *(us4*)&Wt[(size_t)(n0 + nr) * K + k0 + kc4] = w;
}

// ---------------------------------------------------------------------------
// bf16 GEMM: C[M][N] = A[M][K] @ Bt[N][K]^T. A,Bt bf16 row-major (K-contig).
// 128x128 tile, BK=32. Explicit us8 staging: global 16B load -> ds_write_b128
// at byte offset tid*16 (stride-1, conflict-free). Unpadded [row][32] LDS.
// Output fp32 (Cf) or bf16 (Cb) — exactly one non-null.
// ---------------------------------------------------------------------------
__global__ __launch_bounds__(256) void gemm_bt(const unsigned short* __restrict__ A,
                                               const unsigned short* __restrict__ Bt,
                                               float* __restrict__ Cf,
                                               unsigned short* __restrict__ Cb,
                                               int M, int N, int K) {
    __shared__ __align__(16) unsigned short As[128 * 32];
    __shared__ __align__(16) unsigned short Bs[128 * 32];
    const int t = threadIdx.x;
    const int m0 = blockIdx.y * 128, n0 = blockIdx.x * 128;
    const int wave = t >> 6, lane = t & 63;
    const int quad = lane >> 4, l16 = lane & 15;
    const int wm = (wave >> 1) * 64, wn = (wave & 1) * 64;
    const int srow = t >> 2, scol = (t & 3) * 8;

    f32x4 acc[4][4] = {};

    for (int k0 = 0; k0 < K; k0 += 32) {
        us8 a0 = *(const us8*)&A[(size_t)(m0 + srow) * K + k0 + scol];
        us8 a1 = *(const us8*)&A[(size_t)(m0 + srow + 64) * K + k0 + scol];
        us8 b0 = *(const us8*)&Bt[(size_t)(n0 + srow) * K + k0 + scol];
        us8 b1 = *(const us8*)&Bt[(size_t)(n0 + srow + 64) * K + k0 + scol];
        __syncthreads();
        *(us8*)&As[srow * 32 + scol] = a0;
        *(us8*)&As[(srow + 64) * 32 + scol] = a1;
        *(us8*)&Bs[srow * 32 + scol] = b0;
        *(us8*)&Bs[(srow + 64) * 32 + scol] = b1;
        __syncthreads();

        bf16x8 af[4], bfr[4];
#pragma unroll
        for (int i = 0; i < 4; ++i)
            af[i] = *(const bf16x8*)&As[(wm + i * 16 + l16) * 32 + quad * 8];
#pragma unroll
        for (int j = 0; j < 4; ++j)
            bfr[j] = *(const bf16x8*)&Bs[(wn + j * 16 + l16) * 32 + quad * 8];
#pragma unroll
        for (int i = 0; i < 4; ++i)
#pragma unroll
            for (int j = 0; j < 4; ++j)
                acc[i][j] = __builtin_amdgcn_mfma_f32_16x16x32_bf16(af[i], bfr[j], acc[i][j], 0, 0, 0);
    }

    if (Cb) {
#pragma unroll
        for (int i = 0; i < 4; ++i)
#pragma unroll
            for (int j = 0; j < 4; ++j)
#pragma unroll
                for (int r = 0; r < 4; ++r)
                    Cb[(size_t)(m0 + wm + i * 16 + quad * 4 + r) * N + n0 + wn + j * 16 + l16] = f2bf(acc[i][j][r]);
    } else {
#pragma unroll
        for (int i = 0; i < 4; ++i)
#pragma unroll
            for (int j = 0; j < 4; ++j)
#pragma unroll
                for (int r = 0; r < 4; ++r)
                    Cf[(size_t)(m0 + wm + i * 16 + quad * 4 + r) * N + n0 + wn + j * 16 + l16] = acc[i][j][r];
    }
}

// ---------------------------------------------------------------------------
// T = X @ Wgk1 (fp32, K=2048, N=16), LDS-staged.
// ---------------------------------------------------------------------------
__global__ __launch_bounds__(256) void gemm_n16(const float* __restrict__ X,
                                                const float* __restrict__ W,
                                                float* __restrict__ T) {
    __shared__ float Xs[16][129];
    __shared__ float Wsh[128][17];
    const int t = threadIdx.x;
    const int m0 = blockIdx.x * 16;
    const int mm = t >> 4, jj = t & 15;
    float acc = 0.f;
    for (int k0 = 0; k0 < HD_; k0 += 128) {
        __syncthreads();
#pragma unroll
        for (int p = 0; p < 2; ++p) {
            int q = t + p * 256;
            int r = q >> 5, c4 = (q & 31) * 4;
            float4 a = *(const float4*)&X[(size_t)(m0 + r) * HD_ + k0 + c4];
            Xs[r][c4 + 0] = a.x; Xs[r][c4 + 1] = a.y; Xs[r][c4 + 2] = a.z; Xs[r][c4 + 3] = a.w;
        }
#pragma unroll
        for (int p = 0; p < 8; ++p) {
            int q = t + p * 256;
            int r = q >> 4, c = q & 15;
            Wsh[r][c] = W[(size_t)(k0 + r) * 16 + c];
        }
        __syncthreads();
#pragma unroll 16
        for (int kk = 0; kk < 128; ++kk) acc += Xs[mm][kk] * Wsh[kk][jj];
    }
    T[(size_t)(m0 + mm) * 16 + jj] = acc;
}

// ---------------------------------------------------------------------------
// gk = log_sigmoid(T @ Wgk2 + bgk2) / 16.
// ---------------------------------------------------------------------------
__global__ __launch_bounds__(256) void gk_act(const float* __restrict__ T,
                                              const float* __restrict__ W2,
                                              const float* __restrict__ b2,
                                              float* __restrict__ gk) {
    const int idx = blockIdx.x * 256 + threadIdx.x;
    const int n = idx & 1023;
    const int m = idx >> 10;
    float acc = b2[n];
#pragma unroll
    for (int j = 0; j < 16; ++j) acc += T[m * 16 + j] * W2[j * 1024 + n];
    float ls = (acc < 0.f) ? (acc - log1pf(expf(acc))) : (-log1pf(expf(-acc)));
    gk[idx] = ls * 0.0625f;  // / GATE_NORMALIZER
}

// ---------------------------------------------------------------------------
// Gate prep: qg = q*exp(gc)*scale, kg = k*exp(-gc) (bf16 in/out);
// gle = exp(gc_last). One thread per (b,h,chunk,d) chain.
// ---------------------------------------------------------------------------
__global__ __launch_bounds__(256) void gate_prep(const unsigned short* __restrict__ qb,
                                                 const unsigned short* __restrict__ kb,
                                                 const float* __restrict__ gk,
                                                 unsigned short* __restrict__ qg,
                                                 unsigned short* __restrict__ kg,
                                                 float* __restrict__ glexp) {
    const int idx = blockIdx.x * 256 + threadIdx.x;
    const int d = idx & 255;
    const int chunk = (idx >> 8) & 31;
    const int h = (idx >> 13) & 3;
    const int b = idx >> 15;
    const size_t col = h * 256 + d;
    const size_t rowbase = (size_t)b * S_ + chunk * 64;
    const float scale = 0.0625f;  // DK^-0.5
    float gc = 0.f;
    for (int t = 0; t < 64; ++t) {
        size_t off = (rowbase + t) * (size_t)KD_ + col;
        gc += gk[off];
        qg[off] = f2bf(bf2f(qb[off]) * expf(gc) * scale);
        kg[off] = f2bf(bf2f(kb[off]) * expf(-gc));
    }
    glexp[idx] = expf(gc);
}

// ---------------------------------------------------------------------------
// Pass C1: A_s[bhc][t][j] = tril(q_g k_g^T) (64x64, K=256) -> bf16.
// ---------------------------------------------------------------------------
__global__ __launch_bounds__(256) void pass_c1(const unsigned short* __restrict__ qg,
                                               const unsigned short* __restrict__ kg,
                                               unsigned short* __restrict__ Asg) {
    __shared__ __align__(16) unsigned short Aq[64 * 32];
    __shared__ __align__(16) unsigned short Bk[64 * 32];
    const int t = threadIdx.x;
    const int bhc = blockIdx.x;
    const int chunk = bhc & 31, bh = bhc >> 5;
    const int h = bh & 3, b = bh >> 2;
    const int s0 = chunk * 64;
    const int wave = t >> 6, lane = t & 63;
    const int quad = lane >> 4, l16 = lane & 15;
    const int srow = t >> 2, scol = (t & 3) * 8;
    const size_t base = (size_t)b * S_ * KD_ + h * DK_;

    f32x4 acc[4] = {};

    for (int k0 = 0; k0 < 256; k0 += 32) {
        us8 aq = *(const us8*)&qg[base + (size_t)(s0 + srow) * KD_ + k0 + scol];
        us8 bk = *(const us8*)&kg[base + (size_t)(s0 + srow) * KD_ + k0 + scol];
        __syncthreads();
        *(us8*)&Aq[srow * 32 + scol] = aq;
        *(us8*)&Bk[srow * 32 + scol] = bk;
        __syncthreads();
        bf16x8 bfr = *(const bf16x8*)&Bk[(wave * 16 + l16) * 32 + quad * 8];
#pragma unroll
        for (int i = 0; i < 4; ++i) {
            bf16x8 af = *(const bf16x8*)&Aq[(i * 16 + l16) * 32 + quad * 8];
            acc[i] = __builtin_amdgcn_mfma_f32_16x16x32_bf16(af, bfr, acc[i], 0, 0, 0);
        }
    }

    const int j = wave * 16 + l16;
#pragma unroll
    for (int i = 0; i < 4; ++i)
#pragma unroll
        for (int r = 0; r < 4; ++r) {
            int m = i * 16 + quad * 4 + r;
            float val = (j <= m) ? acc[i][r] : 0.f;
            Asg[(size_t)bhc * 4096 + m * 64 + j] = f2bf(val);
        }
}

// ---------------------------------------------------------------------------
// Pass A: Dt[bhc][e][d] = sum_t v[t,e]*k_g[t,d] (bf16 in/out).
// grid(x=2 dn, y=4 em, z=256 bhc)
// ---------------------------------------------------------------------------
__global__ __launch_bounds__(256) void pass_a(const unsigned short* __restrict__ kg,
                                              const unsigned short* __restrict__ vb,
                                              unsigned short* __restrict__ Dt) {
    __shared__ __align__(16) unsigned short As[128][40];  // [e][t]
    __shared__ __align__(16) unsigned short Bs[128][40];  // [d][t]
    const int t = threadIdx.x;
    const int bhc = blockIdx.z;
    const int chunk = bhc & 31, bh = bhc >> 5;
    const int h = bh & 3, b = bh >> 2;
    const int s0 = chunk * 64;
    const int e0 = blockIdx.y * 128;
    const int d0 = blockIdx.x * 128;
    const int wave = t >> 6, lane = t & 63;
    const int quad = lane >> 4, l16 = lane & 15;
    const int wm = (wave >> 1) * 64, wn = (wave & 1) * 64;

    f32x4 acc[4][4] = {};

    for (int k0 = 0; k0 < 64; k0 += 32) {
        __syncthreads();
#pragma unroll
        for (int p = 0; p < 2; ++p) {
            int q = t + p * 256;
            int tt = q >> 4, e8 = q & 15;
            us8 w = *(const us8*)&vb[((size_t)b * S_ + s0 + k0 + tt) * VD_ + h * DV_ + e0 + e8 * 8];
#pragma unroll
            for (int u = 0; u < 8; ++u) As[e8 * 8 + u][tt] = w[u];
        }
#pragma unroll
        for (int p = 0; p < 2; ++p) {
            int q = t + p * 256;
            int tt = q >> 4, d8 = q & 15;
            us8 w = *(const us8*)&kg[((size_t)b * S_ + s0 + k0 + tt) * KD_ + h * DK_ + d0 + d8 * 8];
#pragma unroll
            for (int u = 0; u < 8; ++u) Bs[d8 * 8 + u][tt] = w[u];
        }
        __syncthreads();

        bf16x8 af[4], bfr[4];
#pragma unroll
        for (int i = 0; i < 4; ++i)
            af[i] = *(const bf16x8*)&As[wm + i * 16 + l16][quad * 8];
#pragma unroll
        for (int j = 0; j < 4; ++j)
            bfr[j] = *(const bf16x8*)&Bs[wn + j * 16 + l16][quad * 8];
#pragma unroll
        for (int i = 0; i < 4; ++i)
#pragma unroll
            for (int j = 0; j < 4; ++j)
                acc[i][j] = __builtin_amdgcn_mfma_f32_16x16x32_bf16(af[i], bfr[j], acc[i][j], 0, 0, 0);
    }

#pragma unroll
    for (int i = 0; i < 4; ++i)
#pragma unroll
        for (int j = 0; j < 4; ++j)
#pragma unroll
            for (int r = 0; r < 4; ++r) {
                size_t e = e0 + wm + i * 16 + quad * 4 + r;
                size_t d = d0 + wn + j * 16 + l16;
                Dt[((size_t)bhc * 512 + e) * 256 + d] = f2bf(acc[i][j][r]);
            }
}

// ---------------------------------------------------------------------------
// Pass B: diagonal scan over chunks; write entering state S^T per chunk.
// ---------------------------------------------------------------------------
__global__ __launch_bounds__(256) void pass_b(const unsigned short* __restrict__ Dt,
                                              const float* __restrict__ gle,
                                              unsigned short* __restrict__ St) {
    const int gid = blockIdx.x * 256 + threadIdx.x;
    const int bh = gid >> 14;
    const int rem = gid & 16383;
    const int e = rem >> 5;
    const int d8 = (rem & 31) * 8;

    float S[8];
#pragma unroll
    for (int i = 0; i < 8; ++i) S[i] = 0.f;

    for (int n = 0; n < NCHUNK_; ++n) {
        const size_t row = (((size_t)(bh * 32 + n)) * 512 + e) * 256 + d8;
        us8 w;
#pragma unroll
        for (int i = 0; i < 8; ++i) w[i] = f2bf(S[i]);
        *(us8*)&St[row] = w;
        us8 dv = *(const us8*)&Dt[row];
        float4 e0 = *(const float4*)&gle[(size_t)(bh * 32 + n) * 256 + d8];
        float4 e1 = *(const float4*)&gle[(size_t)(bh * 32 + n) * 256 + d8 + 4];
        float E[8] = {e0.x, e0.y, e0.z, e0.w, e1.x, e1.y, e1.z, e1.w};
#pragma unroll
        for (int i = 0; i < 8; ++i) S[i] = (S[i] + bf2f(dv[i])) * E[i];
    }
}

// ---------------------------------------------------------------------------
// Pass C2: o[t][e] = [A_s | q_g][t][:] @ [v ; S^T][:][e]  (K=320), fp32 out.
// grid(x=2 e-half, z=256 bhc).
// ---------------------------------------------------------------------------
__global__ __launch_bounds__(256) void pass_c2(const unsigned short* __restrict__ qg,
                                               const unsigned short* __restrict__ vb,
                                               const unsigned short* __restrict__ Asg,
                                               const unsigned short* __restrict__ St,
                                               float* __restrict__ o) {
    __shared__ __align__(16) unsigned short At[64][40];   // [t][k]
    __shared__ __align__(16) unsigned short Bt[256][40];  // [e][k]
    const int t = threadIdx.x;
    const int bhc = blockIdx.z;
    const int chunk = bhc & 31, bh = bhc >> 5;
    const int h = bh & 3, b = bh >> 2;
    const int s0 = chunk * 64;
    const int eh = blockIdx.x * 256;
    const int wave = t >> 6, lane = t & 63;
    const int quad = lane >> 4, l16 = lane & 15;
    const int we = wave * 64;

    f32x4 acc[4][4] = {};

    for (int kk0 = 0; kk0 < 10; ++kk0) {
        __syncthreads();
        if (kk0 < 2) {
            {
                int row = t >> 2, c8 = t & 3;
                us8 w = *(const us8*)&Asg[(size_t)bhc * 4096 + row * 64 + kk0 * 32 + c8 * 8];
                *(us8*)&At[row][c8 * 8] = w;
            }
            const int t0 = kk0 * 32;
#pragma unroll
            for (int p = 0; p < 4; ++p) {
                int q = t + p * 256;
                int kk = q >> 5, e8 = q & 31;
                us8 w = *(const us8*)&vb[((size_t)b * S_ + s0 + t0 + kk) * VD_ + h * DV_ + eh + e8 * 8];
#pragma unroll
                for (int u = 0; u < 8; ++u) Bt[e8 * 8 + u][kk] = w[u];
            }
        } else {
            const int d0 = (kk0 - 2) * 32;
            {
                int row = t >> 2, c8 = t & 3;
                us8 w = *(const us8*)&qg[((size_t)b * S_ + s0 + row) * KD_ + h * DK_ + d0 + c8 * 8];
                *(us8*)&At[row][c8 * 8] = w;
            }
#pragma unroll
            for (int p = 0; p < 4; ++p) {
                int q = t + p * 256;
                int row = q >> 2, c8 = q & 3;
                us8 w = *(const us8*)&St[(((size_t)bhc) * 512 + eh + row) * 256 + d0 + c8 * 8];
                *(us8*)&Bt[row][c8 * 8] = w;
            }
        }
        __syncthreads();

        bf16x8 af[4], bfr[4];
#pragma unroll
        for (int i = 0; i < 4; ++i)
            af[i] = *(const bf16x8*)&At[i * 16 + l16][quad * 8];
#pragma unroll
        for (int j = 0; j < 4; ++j)
            bfr[j] = *(const bf16x8*)&Bt[we + j * 16 + l16][quad * 8];
#pragma unroll
        for (int i = 0; i < 4; ++i)
#pragma unroll
            for (int j = 0; j < 4; ++j)
                acc[i][j] = __builtin_amdgcn_mfma_f32_16x16x32_bf16(af[i], bfr[j], acc[i][j], 0, 0, 0);
    }

#pragma unroll
    for (int i = 0; i < 4; ++i)
#pragma unroll
        for (int j = 0; j < 4; ++j)
#pragma unroll
            for (int r = 0; r < 4; ++r) {
                int m = i * 16 + quad * 4 + r;
                int e = eh + we + j * 16 + l16;
                o[((size_t)b * S_ + s0 + m) * VD_ + h * DV_ + e] = acc[i][j][r];
            }
}

// ---------------------------------------------------------------------------
// Post: RMS-norm over Dv=512 per (b,s,h) + gated swish; fp32 o in, bf16 out.
// ---------------------------------------------------------------------------
__global__ __launch_bounds__(256) void postnorm(const float* __restrict__ o,
                                                const unsigned short* __restrict__ g,
                                                const float* __restrict__ gnw,
                                                unsigned short* __restrict__ obf) {
    const int row = blockIdx.x;
    const int wave = threadIdx.x >> 6;
    const int lane = threadIdx.x & 63;
    const size_t base = (size_t)row * VD_ + wave * 512;
    float x[8];
    float ss = 0.f;
#pragma unroll
    for (int j = 0; j < 8; ++j) {
        x[j] = o[base + lane + j * 64];
        ss += x[j] * x[j];
    }
#pragma unroll
    for (int off = 32; off; off >>= 1) ss += __shfl_xor(ss, off);
    const float inv = 1.0f / sqrtf(ss * (1.0f / 512.0f) + 1e-5f);
#pragma unroll
    for (int j = 0; j < 8; ++j) {
        int e = lane + j * 64;
        float gv = bf2f(g[base + e]);
        float sig = 1.0f / (1.0f + expf(-gv));
        obf[base + e] = f2bf(x[j] * inv * gnw[e] * (gv * sig));
    }
}

// ---------------------------------------------------------------------------
extern "C" void kernel_launch(void* const* d_in, const int* in_sizes, int n_in,
                              void* d_out, int out_size, void* d_ws, size_t ws_size,
                              hipStream_t stream) {
    const float* x    = (const float*)d_in[0];
    const float* Wq   = (const float*)d_in[1];
    const float* Wk   = (const float*)d_in[2];
    const float* Wv   = (const float*)d_in[3];
    const float* Wgk1 = (const float*)d_in[4];
    const float* Wgk2 = (const float*)d_in[5];
    const float* bgk2 = (const float*)d_in[6];
    const float* Wg   = (const float*)d_in[7];
    const float* gnw  = (const float*)d_in[8];
    const float* Wo   = (const float*)d_in[9];
    float* out = (float*)d_out;

    float* ws = (float*)d_ws;
    const size_t MF = 1048576;
    typedef unsigned short us;
    // --- Region A (long-lived): 0..33M floats ---
    us* xb     = (us*)(ws);              // x bf16 [4096][2048]     0..4M
    us* Wgt    = (us*)(ws + 4 * MF);     // Wg^T bf16 [2048][2048]  4..6M
    us* Wot    = (us*)(ws + 6 * MF);     // Wo^T bf16 [2048][2048]  6..8M
    us* vb     = (us*)(ws + 8 * MF);     // v bf16 [4096][2048]     8..12M
    us* qg     = (us*)(ws + 12 * MF);    // gated q bf16            12..14M
    us* kg     = (us*)(ws + 14 * MF);    // gated k bf16            14..16M
    float* T   = ws + 16 * MF;           // 65536
    float* gle = T + 65536;              // 65536
    us* Asg    = (us*)(ws + 16 * MF + 131072);  // 1M shorts (0.5M floats)
    us* St     = (us*)(ws + 17 * MF);    // S^T bf16 32M shorts     17..33M
    // --- Region B (lifetime-shared): 33..49M floats ---
    us* qb     = (us*)(ws + 33 * MF);    // q bf16 (dead after gate_prep) 33..35M
    us* kb     = (us*)(ws + 35 * MF);    // k bf16 (dead after gate_prep) 35..37M
    us* Wqt    = (us*)(ws + 37 * MF);    // Wq^T bf16 (dead after proj)   37..38M
    us* Wkt    = (us*)(ws + 38 * MF);    // Wk^T bf16                     38..39M
    us* Wvt    = (us*)(ws + 39 * MF);    // Wv^T bf16                     39..41M
    float* gkb = ws + 41 * MF;           // gk fp32 (dead after gate_prep) 41..45M
    us* Dt     = (us*)(ws + 33 * MF);    // D^T bf16 (after gate_prep; dead after pass_b) 33..49M
    float* o   = ws + 33 * MF;           // o fp32 (after pass_b)   33..41M
    us* gb     = (us*)(ws + 41 * MF);    // g bf16 (after pass_b)   41..45M
    us* obf    = (us*)(ws + 45 * MF);    // normed o bf16           45..49M

    dim3 blk(256);
    conv_bf16<<<8192, blk, 0, stream>>>(x, xb);
    tr_w<<<dim3(32, 64), blk, 0, stream>>>(Wq, Wqt, HD_, KD_);
    tr_w<<<dim3(32, 64), blk, 0, stream>>>(Wk, Wkt, HD_, KD_);
    tr_w<<<dim3(64, 64), blk, 0, stream>>>(Wv, Wvt, HD_, VD_);
    tr_w<<<dim3(64, 64), blk, 0, stream>>>(Wg, Wgt, HD_, VD_);
    tr_w<<<dim3(64, 64), blk, 0, stream>>>(Wo, Wot, VD_, HD_);  // Wo: [K=2048 value][N=2048 hidden]

    gemm_bt<<<dim3(16, 32), blk, 0, stream>>>(xb, Wvt, nullptr, vb, M_, VD_, HD_);
    gemm_bt<<<dim3(8, 32),  blk, 0, stream>>>(xb, Wqt, nullptr, qb, M_, KD_, HD_);
    gemm_bt<<<dim3(8, 32),  blk, 0, stream>>>(xb, Wkt, nullptr, kb, M_, KD_, HD_);
    gemm_n16<<<M_ / 16, blk, 0, stream>>>(x, Wgk1, T);
    gk_act<<<(M_ * KD_) / 256, blk, 0, stream>>>(T, Wgk2, bgk2, gkb);
    gate_prep<<<(B_ * H_ * NCHUNK_ * DK_) / 256, blk, 0, stream>>>(qb, kb, gkb, qg, kg, gle);

    pass_c1<<<256, blk, 0, stream>>>(qg, kg, Asg);
    pass_a<<<dim3(2, 4, 256), blk, 0, stream>>>(kg, vb, Dt);
    pass_b<<<512, blk, 0, stream>>>(Dt, gle, St);
    gemm_bt<<<dim3(16, 32), blk, 0, stream>>>(xb, Wgt, nullptr, gb, M_, VD_, HD_);
    pass_c2<<<dim3(2, 1, 256), blk, 0, stream>>>(qg, vb, Asg, St, o);
    postnorm<<<M_, blk, 0, stream>>>(o, gb, gnw, obf);
    // Output projection: K is value_dim = VD_ (2048). (R4/R5 bug: VD_*H_ read 4x OOB.)
    gemm_bt<<<dim3(16, 32), blk, 0, stream>>>(obf, Wot, out, nullptr, M_, HD_, VD_);
}

// Round 7
// 507.721 us; speedup vs baseline: 8.6192x; 1.2108x over previous
//
#include <hip/hip_runtime.h>
#include <hip/hip_bf16.h>

// Problem constants
#define B_   2
#define S_   2048
#define HD_  2048
#define H_   4
#define DK_  256
#define DV_  512
#define KD_  1024   // H_*DK_
#define VD_  2048   // H_*DV_
#define ND_  6144   // fused N: q(1024) | k(1024) | v(2048) | g(2048)
#define M_   4096   // B_*S_
#define NCHUNK_ 32
#define CHUNK_  64

typedef __attribute__((ext_vector_type(8))) short bf16x8;
typedef __attribute__((ext_vector_type(4))) float f32x4;
typedef __attribute__((ext_vector_type(4))) unsigned short us4;
typedef __attribute__((ext_vector_type(8))) unsigned short us8;

__device__ __forceinline__ unsigned short f2bf(float f) {
    __hip_bfloat16 h = __float2bfloat16(f);
    return *reinterpret_cast<unsigned short*>(&h);
}
__device__ __forceinline__ float bf2f(unsigned short u) {
    unsigned int x = ((unsigned int)u) << 16;
    return *reinterpret_cast<float*>(&x);
}

// ---------------------------------------------------------------------------
// fp32 -> bf16 flat convert (x). One float4 per thread.
// ---------------------------------------------------------------------------
__global__ __launch_bounds__(256) void conv_bf16(const float* __restrict__ in,
                                                 unsigned short* __restrict__ out) {
    const int idx = blockIdx.x * 256 + threadIdx.x;
    float4 a = *(const float4*)&in[(size_t)idx * 4];
    us4 w; w.x = f2bf(a.x); w.y = f2bf(a.y); w.z = f2bf(a.z); w.w = f2bf(a.w);
    *(us4*)&out[(size_t)idx * 4] = w;
}

// ---------------------------------------------------------------------------
// Weight transpose: Wt[n][k](bf16) = W[k][n](fp32). 32x32 tiles via LDS.
// ---------------------------------------------------------------------------
__global__ __launch_bounds__(256) void tr_w(const float* __restrict__ W,
                                            unsigned short* __restrict__ Wt,
                                            int K, int N) {
    __shared__ float Ws[32][33];
    const int t = threadIdx.x;
    const int n0 = blockIdx.x * 32, k0 = blockIdx.y * 32;
    const int r = t >> 3, c4 = (t & 7) * 4;
    float4 a = *(const float4*)&W[(size_t)(k0 + r) * N + n0 + c4];
    Ws[r][c4 + 0] = a.x; Ws[r][c4 + 1] = a.y; Ws[r][c4 + 2] = a.z; Ws[r][c4 + 3] = a.w;
    __syncthreads();
    const int nr = t >> 3, kc4 = (t & 7) * 4;
    us4 w;
#pragma unroll
    for (int j = 0; j < 4; ++j) w[j] = f2bf(Ws[kc4 + j][nr]);
    *(us4*)&Wt[(size_t)(n0 + nr) * K + k0 + kc4] = w;
}

// ---------------------------------------------------------------------------
// v transpose: vT[((b*H+h)*512+e)*2048 + s] = qkvg[(b*2048+s)*6144 + 2048 + h*512 + e]
// bf16 in/out, 32x32 tiles. grid(x = 64 e-tiles, y = 128 s-tiles).
// ---------------------------------------------------------------------------
__global__ __launch_bounds__(256) void tr_v(const unsigned short* __restrict__ qkvg,
                                            unsigned short* __restrict__ vT) {
    __shared__ unsigned short Ws[32][36];
    const int t = threadIdx.x;
    const int c0 = blockIdx.x * 32;      // v-col within VD (0..2047)
    const int s0 = blockIdx.y * 32;      // global s (0..4095)
    {
        const int r = t >> 3, c4 = (t & 7) * 4;
        us4 w = *(const us4*)&qkvg[(size_t)(s0 + r) * ND_ + 2048 + c0 + c4];
        *(us4*)&Ws[r][c4] = w;
    }
    __syncthreads();
    const int er = t >> 3, sc4 = (t & 7) * 4;
    const int c = c0 + er;
    const int h = c >> 9, e = c & 511;
    const int b = s0 >> 11, srow = s0 & 2047;
    us4 w;
#pragma unroll
    for (int j = 0; j < 4; ++j) w[j] = Ws[sc4 + j][er];
    *(us4*)&vT[((size_t)(b * H_ + h) * 512 + e) * 2048 + srow + sc4] = w;
}

// ---------------------------------------------------------------------------
// bf16 GEMM: C[M][N] = A[M][K] @ Bt[N][K]^T. A,Bt bf16 row-major (K-contig).
// 128x128 tile, BK=32, register-prefetch pipelining (next tile's global loads
// issue before the MFMA block). Unpadded [row*32] LDS, conflict-free.
// ---------------------------------------------------------------------------
__global__ __launch_bounds__(256) void gemm_bt(const unsigned short* __restrict__ A,
                                               const unsigned short* __restrict__ Bt,
                                               float* __restrict__ Cf,
                                               unsigned short* __restrict__ Cb,
                                               int M, int N, int K) {
    __shared__ __align__(16) unsigned short As[128 * 32];
    __shared__ __align__(16) unsigned short Bs[128 * 32];
    const int t = threadIdx.x;
    const int m0 = blockIdx.y * 128, n0 = blockIdx.x * 128;
    const int wave = t >> 6, lane = t & 63;
    const int quad = lane >> 4, l16 = lane & 15;
    const int wm = (wave >> 1) * 64, wn = (wave & 1) * 64;
    const int srow = t >> 2, scol = (t & 3) * 8;

    f32x4 acc[4][4] = {};

    us8 a0 = *(const us8*)&A[(size_t)(m0 + srow) * K + scol];
    us8 a1 = *(const us8*)&A[(size_t)(m0 + srow + 64) * K + scol];
    us8 b0 = *(const us8*)&Bt[(size_t)(n0 + srow) * K + scol];
    us8 b1 = *(const us8*)&Bt[(size_t)(n0 + srow + 64) * K + scol];

    for (int k0 = 0; k0 < K; k0 += 32) {
        __syncthreads();
        *(us8*)&As[srow * 32 + scol] = a0;
        *(us8*)&As[(srow + 64) * 32 + scol] = a1;
        *(us8*)&Bs[srow * 32 + scol] = b0;
        *(us8*)&Bs[(srow + 64) * 32 + scol] = b1;
        __syncthreads();
        if (k0 + 32 < K) {
            a0 = *(const us8*)&A[(size_t)(m0 + srow) * K + k0 + 32 + scol];
            a1 = *(const us8*)&A[(size_t)(m0 + srow + 64) * K + k0 + 32 + scol];
            b0 = *(const us8*)&Bt[(size_t)(n0 + srow) * K + k0 + 32 + scol];
            b1 = *(const us8*)&Bt[(size_t)(n0 + srow + 64) * K + k0 + 32 + scol];
        }

        bf16x8 af[4], bfr[4];
#pragma unroll
        for (int i = 0; i < 4; ++i)
            af[i] = *(const bf16x8*)&As[(wm + i * 16 + l16) * 32 + quad * 8];
#pragma unroll
        for (int j = 0; j < 4; ++j)
            bfr[j] = *(const bf16x8*)&Bs[(wn + j * 16 + l16) * 32 + quad * 8];
#pragma unroll
        for (int i = 0; i < 4; ++i)
#pragma unroll
            for (int j = 0; j < 4; ++j)
                acc[i][j] = __builtin_amdgcn_mfma_f32_16x16x32_bf16(af[i], bfr[j], acc[i][j], 0, 0, 0);
    }

    if (Cb) {
#pragma unroll
        for (int i = 0; i < 4; ++i)
#pragma unroll
            for (int j = 0; j < 4; ++j)
#pragma unroll
                for (int r = 0; r < 4; ++r)
                    Cb[(size_t)(m0 + wm + i * 16 + quad * 4 + r) * N + n0 + wn + j * 16 + l16] = f2bf(acc[i][j][r]);
    } else {
#pragma unroll
        for (int i = 0; i < 4; ++i)
#pragma unroll
            for (int j = 0; j < 4; ++j)
#pragma unroll
                for (int r = 0; r < 4; ++r)
                    Cf[(size_t)(m0 + wm + i * 16 + quad * 4 + r) * N + n0 + wn + j * 16 + l16] = acc[i][j][r];
    }
}

// ---------------------------------------------------------------------------
// T = X @ Wgk1 (fp32, K=2048, N=16), LDS-staged.
// ---------------------------------------------------------------------------
__global__ __launch_bounds__(256) void gemm_n16(const float* __restrict__ X,
                                                const float* __restrict__ W,
                                                float* __restrict__ T) {
    __shared__ float Xs[16][129];
    __shared__ float Wsh[128][17];
    const int t = threadIdx.x;
    const int m0 = blockIdx.x * 16;
    const int mm = t >> 4, jj = t & 15;
    float acc = 0.f;
    for (int k0 = 0; k0 < HD_; k0 += 128) {
        __syncthreads();
#pragma unroll
        for (int p = 0; p < 2; ++p) {
            int q = t + p * 256;
            int r = q >> 5, c4 = (q & 31) * 4;
            float4 a = *(const float4*)&X[(size_t)(m0 + r) * HD_ + k0 + c4];
            Xs[r][c4 + 0] = a.x; Xs[r][c4 + 1] = a.y; Xs[r][c4 + 2] = a.z; Xs[r][c4 + 3] = a.w;
        }
#pragma unroll
        for (int p = 0; p < 8; ++p) {
            int q = t + p * 256;
            int r = q >> 4, c = q & 15;
            Wsh[r][c] = W[(size_t)(k0 + r) * 16 + c];
        }
        __syncthreads();
#pragma unroll 16
        for (int kk = 0; kk < 128; ++kk) acc += Xs[mm][kk] * Wsh[kk][jj];
    }
    T[(size_t)(m0 + mm) * 16 + jj] = acc;
}

// ---------------------------------------------------------------------------
// gk = log_sigmoid(T @ Wgk2 + bgk2) / 16.
// ---------------------------------------------------------------------------
__global__ __launch_bounds__(256) void gk_act(const float* __restrict__ T,
                                              const float* __restrict__ W2,
                                              const float* __restrict__ b2,
                                              float* __restrict__ gk) {
    const int idx = blockIdx.x * 256 + threadIdx.x;
    const int n = idx & 1023;
    const int m = idx >> 10;
    float acc = b2[n];
#pragma unroll
    for (int j = 0; j < 16; ++j) acc += T[m * 16 + j] * W2[j * 1024 + n];
    float ls = (acc < 0.f) ? (acc - log1pf(expf(acc))) : (-log1pf(expf(-acc)));
    gk[idx] = ls * 0.0625f;  // / GATE_NORMALIZER
}

// ---------------------------------------------------------------------------
// Gate prep: reads q,k columns of fused qkvg (stride ND_); writes
// qg,kg (compact t-major), kgT (d-major: [bh*256+d][s]), gle.
// ---------------------------------------------------------------------------
__global__ __launch_bounds__(256) void gate_prep(const unsigned short* __restrict__ qkvg,
                                                 const float* __restrict__ gk,
                                                 unsigned short* __restrict__ qg,
                                                 unsigned short* __restrict__ kg,
                                                 unsigned short* __restrict__ kgT,
                                                 float* __restrict__ glexp) {
    const int idx = blockIdx.x * 256 + threadIdx.x;
    const int d = idx & 255;
    const int chunk = (idx >> 8) & 31;
    const int h = (idx >> 13) & 3;
    const int b = idx >> 15;
    const int bh = b * H_ + h;
    const size_t col = h * 256 + d;
    const size_t rowbase = (size_t)b * S_ + chunk * 64;
    const size_t kgT_base = ((size_t)bh * 256 + d) * 2048 + chunk * 64;
    const float scale = 0.0625f;  // DK^-0.5
    float gc = 0.f;
    for (int t = 0; t < 64; ++t) {
        size_t r = rowbase + t;
        gc += gk[r * (size_t)KD_ + col];
        unsigned short qv = qkvg[r * (size_t)ND_ + col];
        unsigned short kv = qkvg[r * (size_t)ND_ + 1024 + col];
        unsigned short kgv = f2bf(bf2f(kv) * expf(-gc));
        qg[r * (size_t)KD_ + col] = f2bf(bf2f(qv) * expf(gc) * scale);
        kg[r * (size_t)KD_ + col] = kgv;
        kgT[kgT_base + t] = kgv;
    }
    glexp[idx] = expf(gc);
}

// ---------------------------------------------------------------------------
// Pass C1: A_s[bhc][t][j] = tril(q_g k_g^T) (64x64, K=256) -> bf16.
// Register-prefetch pipelined.
// ---------------------------------------------------------------------------
__global__ __launch_bounds__(256) void pass_c1(const unsigned short* __restrict__ qg,
                                               const unsigned short* __restrict__ kg,
                                               unsigned short* __restrict__ Asg) {
    __shared__ __align__(16) unsigned short Aq[64 * 32];
    __shared__ __align__(16) unsigned short Bk[64 * 32];
    const int t = threadIdx.x;
    const int bhc = blockIdx.x;
    const int chunk = bhc & 31, bh = bhc >> 5;
    const int h = bh & 3, b = bh >> 2;
    const int s0 = chunk * 64;
    const int wave = t >> 6, lane = t & 63;
    const int quad = lane >> 4, l16 = lane & 15;
    const int srow = t >> 2, scol = (t & 3) * 8;
    const size_t base = (size_t)b * S_ * KD_ + h * DK_ + (size_t)(s0 + srow) * KD_ + scol;

    f32x4 acc[4] = {};
    us8 aq = *(const us8*)&qg[base];
    us8 bk = *(const us8*)&kg[base];

    for (int k0 = 0; k0 < 256; k0 += 32) {
        __syncthreads();
        *(us8*)&Aq[srow * 32 + scol] = aq;
        *(us8*)&Bk[srow * 32 + scol] = bk;
        __syncthreads();
        if (k0 + 32 < 256) {
            aq = *(const us8*)&qg[base + k0 + 32];
            bk = *(const us8*)&kg[base + k0 + 32];
        }
        bf16x8 bfr = *(const bf16x8*)&Bk[(wave * 16 + l16) * 32 + quad * 8];
#pragma unroll
        for (int i = 0; i < 4; ++i) {
            bf16x8 af = *(const bf16x8*)&Aq[(i * 16 + l16) * 32 + quad * 8];
            acc[i] = __builtin_amdgcn_mfma_f32_16x16x32_bf16(af, bfr, acc[i], 0, 0, 0);
        }
    }

    const int j = wave * 16 + l16;
#pragma unroll
    for (int i = 0; i < 4; ++i)
#pragma unroll
        for (int r = 0; r < 4; ++r) {
            int m = i * 16 + quad * 4 + r;
            float val = (j <= m) ? acc[i][r] : 0.f;
            Asg[(size_t)bhc * 4096 + m * 64 + j] = f2bf(val);
        }
}

// ---------------------------------------------------------------------------
// Pass A: Dt[bhc][e][d] = sum_t v[t,e]*k_g[t,d]. A-rows from vT, B-rows from
// kgT — both contiguous us8 staging, conflict-free. grid(2,4,256).
// ---------------------------------------------------------------------------
__global__ __launch_bounds__(256) void pass_a(const unsigned short* __restrict__ kgT,
                                              const unsigned short* __restrict__ vT,
                                              unsigned short* __restrict__ Dt) {
    __shared__ __align__(16) unsigned short As[128 * 32];  // [e][t]
    __shared__ __align__(16) unsigned short Bs[128 * 32];  // [d][t]
    const int t = threadIdx.x;
    const int bhc = blockIdx.z;
    const int chunk = bhc & 31, bh = bhc >> 5;
    const int s0 = chunk * 64;
    const int e0 = blockIdx.y * 128;
    const int d0 = blockIdx.x * 128;
    const int wave = t >> 6, lane = t & 63;
    const int quad = lane >> 4, l16 = lane & 15;
    const int wm = (wave >> 1) * 64, wn = (wave & 1) * 64;

    f32x4 acc[4][4] = {};

    for (int k0 = 0; k0 < 64; k0 += 32) {
        __syncthreads();
#pragma unroll
        for (int p = 0; p < 2; ++p) {
            int q = t + p * 256;
            int row = q >> 2, c8 = (q & 3) * 8;
            us8 wv = *(const us8*)&vT[((size_t)bh * 512 + e0 + row) * 2048 + s0 + k0 + c8];
            *(us8*)&As[row * 32 + c8] = wv;
            us8 wk = *(const us8*)&kgT[((size_t)bh * 256 + d0 + row) * 2048 + s0 + k0 + c8];
            *(us8*)&Bs[row * 32 + c8] = wk;
        }
        __syncthreads();

        bf16x8 af[4], bfr[4];
#pragma unroll
        for (int i = 0; i < 4; ++i)
            af[i] = *(const bf16x8*)&As[(wm + i * 16 + l16) * 32 + quad * 8];
#pragma unroll
        for (int j = 0; j < 4; ++j)
            bfr[j] = *(const bf16x8*)&Bs[(wn + j * 16 + l16) * 32 + quad * 8];
#pragma unroll
        for (int i = 0; i < 4; ++i)
#pragma unroll
            for (int j = 0; j < 4; ++j)
                acc[i][j] = __builtin_amdgcn_mfma_f32_16x16x32_bf16(af[i], bfr[j], acc[i][j], 0, 0, 0);
    }

#pragma unroll
    for (int i = 0; i < 4; ++i)
#pragma unroll
        for (int j = 0; j < 4; ++j)
#pragma unroll
            for (int r = 0; r < 4; ++r) {
                size_t e = e0 + wm + i * 16 + quad * 4 + r;
                size_t d = d0 + wn + j * 16 + l16;
                Dt[((size_t)bhc * 512 + e) * 256 + d] = f2bf(acc[i][j][r]);
            }
}

// ---------------------------------------------------------------------------
// Pass B: in-place diagonal scan on DtSt: read D, overwrite with entering S.
// ---------------------------------------------------------------------------
__global__ __launch_bounds__(256) void pass_b(unsigned short* __restrict__ DtSt,
                                              const float* __restrict__ gle) {
    const int gid = blockIdx.x * 256 + threadIdx.x;
    const int bh = gid >> 14;
    const int rem = gid & 16383;
    const int e = rem >> 5;
    const int d8 = (rem & 31) * 8;

    float S[8];
#pragma unroll
    for (int i = 0; i < 8; ++i) S[i] = 0.f;

    for (int n = 0; n < NCHUNK_; ++n) {
        const size_t row = (((size_t)(bh * 32 + n)) * 512 + e) * 256 + d8;
        us8 dv = *(const us8*)&DtSt[row];         // read D first
        us8 w;
#pragma unroll
        for (int i = 0; i < 8; ++i) w[i] = f2bf(S[i]);
        *(us8*)&DtSt[row] = w;                    // overwrite with entering S
        float4 e0 = *(const float4*)&gle[(size_t)(bh * 32 + n) * 256 + d8];
        float4 e1 = *(const float4*)&gle[(size_t)(bh * 32 + n) * 256 + d8 + 4];
        float E[8] = {e0.x, e0.y, e0.z, e0.w, e1.x, e1.y, e1.z, e1.w};
#pragma unroll
        for (int i = 0; i < 8; ++i) S[i] = (S[i] + bf2f(dv[i])) * E[i];
    }
}

// ---------------------------------------------------------------------------
// Pass C2: o[t][e] = [A_s | q_g][t][:] @ [v ; S^T][:][e]  (K=320), bf16 out.
// v-staging from vT (contiguous rows). grid(x=2 e-half, z=256 bhc).
// ---------------------------------------------------------------------------
__global__ __launch_bounds__(256) void pass_c2(const unsigned short* __restrict__ qg,
                                               const unsigned short* __restrict__ vT,
                                               const unsigned short* __restrict__ Asg,
                                               const unsigned short* __restrict__ St,
                                               unsigned short* __restrict__ o) {
    __shared__ __align__(16) unsigned short At[64 * 32];   // [t][k]
    __shared__ __align__(16) unsigned short Bt[256 * 32];  // [e][k]
    const int t = threadIdx.x;
    const int bhc = blockIdx.z;
    const int chunk = bhc & 31, bh = bhc >> 5;
    const int h = bh & 3, b = bh >> 2;
    const int s0 = chunk * 64;
    const int eh = blockIdx.x * 256;
    const int wave = t >> 6, lane = t & 63;
    const int quad = lane >> 4, l16 = lane & 15;
    const int we = wave * 64;

    f32x4 acc[4][4] = {};

    for (int kk0 = 0; kk0 < 10; ++kk0) {
        __syncthreads();
        if (kk0 < 2) {
            {
                int row = t >> 2, c8 = (t & 3) * 8;
                us8 w = *(const us8*)&Asg[(size_t)bhc * 4096 + row * 64 + kk0 * 32 + c8];
                *(us8*)&At[row * 32 + c8] = w;
            }
            const int t0 = kk0 * 32;
#pragma unroll
            for (int p = 0; p < 4; ++p) {
                int q = t + p * 256;
                int row = q >> 2, c8 = (q & 3) * 8;
                us8 w = *(const us8*)&vT[((size_t)bh * 512 + eh + row) * 2048 + s0 + t0 + c8];
                *(us8*)&Bt[row * 32 + c8] = w;
            }
        } else {
            const int d0 = (kk0 - 2) * 32;
            {
                int row = t >> 2, c8 = (t & 3) * 8;
                us8 w = *(const us8*)&qg[((size_t)b * S_ + s0 + row) * KD_ + h * DK_ + d0 + c8];
                *(us8*)&At[row * 32 + c8] = w;
            }
#pragma unroll
            for (int p = 0; p < 4; ++p) {
                int q = t + p * 256;
                int row = q >> 2, c8 = (q & 3) * 8;
                us8 w = *(const us8*)&St[(((size_t)bhc) * 512 + eh + row) * 256 + d0 + c8];
                *(us8*)&Bt[row * 32 + c8] = w;
            }
        }
        __syncthreads();

        bf16x8 af[4], bfr[4];
#pragma unroll
        for (int i = 0; i < 4; ++i)
            af[i] = *(const bf16x8*)&At[(i * 16 + l16) * 32 + quad * 8];
#pragma unroll
        for (int j = 0; j < 4; ++j)
            bfr[j] = *(const bf16x8*)&Bt[(we + j * 16 + l16) * 32 + quad * 8];
#pragma unroll
        for (int i = 0; i < 4; ++i)
#pragma unroll
            for (int j = 0; j < 4; ++j)
                acc[i][j] = __builtin_amdgcn_mfma_f32_16x16x32_bf16(af[i], bfr[j], acc[i][j], 0, 0, 0);
    }

#pragma unroll
    for (int i = 0; i < 4; ++i)
#pragma unroll
        for (int j = 0; j < 4; ++j)
#pragma unroll
            for (int r = 0; r < 4; ++r) {
                int m = i * 16 + quad * 4 + r;
                int e = eh + we + j * 16 + l16;
                o[((size_t)b * S_ + s0 + m) * VD_ + h * DV_ + e] = f2bf(acc[i][j][r]);
            }
}

// ---------------------------------------------------------------------------
// Post: RMS-norm over Dv=512 per (b,s,h) + gated swish; bf16 o in,
// g from fused qkvg cols (offset 4096, stride ND_), bf16 out.
// ---------------------------------------------------------------------------
__global__ __launch_bounds__(256) void postnorm(const unsigned short* __restrict__ o,
                                                const unsigned short* __restrict__ qkvg,
                                                const float* __restrict__ gnw,
                                                unsigned short* __restrict__ obf) {
    const int row = blockIdx.x;
    const int wave = threadIdx.x >> 6;
    const int lane = threadIdx.x & 63;
    const size_t base = (size_t)row * VD_ + wave * 512;
    const size_t gbase = (size_t)row * ND_ + 4096 + wave * 512;
    float x[8];
    float ss = 0.f;
#pragma unroll
    for (int j = 0; j < 8; ++j) {
        x[j] = bf2f(o[base + lane + j * 64]);
        ss += x[j] * x[j];
    }
#pragma unroll
    for (int off = 32; off; off >>= 1) ss += __shfl_xor(ss, off);
    const float inv = 1.0f / sqrtf(ss * (1.0f / 512.0f) + 1e-5f);
#pragma unroll
    for (int j = 0; j < 8; ++j) {
        int e = lane + j * 64;
        float gv = bf2f(qkvg[gbase + e]);
        float sig = 1.0f / (1.0f + expf(-gv));
        obf[base + e] = f2bf(x[j] * inv * gnw[e] * (gv * sig));
    }
}

// ---------------------------------------------------------------------------
extern "C" void kernel_launch(void* const* d_in, const int* in_sizes, int n_in,
                              void* d_out, int out_size, void* d_ws, size_t ws_size,
                              hipStream_t stream) {
    const float* x    = (const float*)d_in[0];
    const float* Wq   = (const float*)d_in[1];
    const float* Wk   = (const float*)d_in[2];
    const float* Wv   = (const float*)d_in[3];
    const float* Wgk1 = (const float*)d_in[4];
    const float* Wgk2 = (const float*)d_in[5];
    const float* bgk2 = (const float*)d_in[6];
    const float* Wg   = (const float*)d_in[7];
    const float* gnw  = (const float*)d_in[8];
    const float* Wo   = (const float*)d_in[9];
    float* out = (float*)d_out;

    float* ws = (float*)d_ws;
    const size_t MF = 1048576;
    typedef unsigned short us;
    // --- long-lived ---
    us* WotT   = (us*)(ws);                      // [2048][2048] bf16   0..2M
    us* qkvg   = (us*)(ws + 2 * MF);             // [4096][6144] bf16   2..15M (12.58M)
    us* qg     = (us*)(ws + 15 * MF);            // [4096][1024] bf16   15..17M
    us* kg     = (us*)(ws + 17 * MF);            // [4096][1024] bf16   17..19M
    us* kgT    = (us*)(ws + 19 * MF);            // [8*256][2048] bf16  19..21M
    us* vT     = (us*)(ws + 21 * MF);            // [8*512][2048] bf16  21..25M
    float* T   = ws + 25 * MF;                   // 65536
    float* gle = T + 65536;                      // 65536
    us* Asg    = (us*)(ws + 25 * MF + 131072);   // 1M shorts
    us* DtSt   = (us*)(ws + 25 * MF + 786432);   // 32M shorts: 25.75..41.75M
    // --- scratch (lifetime-shared) ---
    us* xb     = (us*)(ws + 41 * MF + 786432);   // x bf16 4M (dead after QKVG GEMM)
    float* gkb = ws + 41 * MF + 786432;          // gk fp32 4M (alias xb; after GEMM, dead after gate_prep)
    us* WcatT  = (us*)(ws + 45 * MF + 786432);   // [6144][2048] bf16 6.29M (dead after QKVG GEMM)
    us* o      = (us*)(ws + 45 * MF + 786432);   // o bf16 4M (alias WcatT; written by pass_c2)
    us* obf    = (us*)(ws + 49 * MF + 786432);   // normed o bf16 2M: 49.75..51.75M

    dim3 blk(256);
    conv_bf16<<<8192, blk, 0, stream>>>(x, xb);
    // concat W^T: rows [0..1024)=Wq, [1024..2048)=Wk, [2048..4096)=Wv, [4096..6144)=Wg
    tr_w<<<dim3(32, 64), blk, 0, stream>>>(Wq, WcatT,                   HD_, KD_);
    tr_w<<<dim3(32, 64), blk, 0, stream>>>(Wk, WcatT + 1024 * 2048,     HD_, KD_);
    tr_w<<<dim3(64, 64), blk, 0, stream>>>(Wv, WcatT + 2048 * 2048,     HD_, VD_);
    tr_w<<<dim3(64, 64), blk, 0, stream>>>(Wg, WcatT + (size_t)4096 * 2048, HD_, VD_);
    tr_w<<<dim3(64, 64), blk, 0, stream>>>(Wo, WotT, VD_, HD_);

    // fused projection: qkvg = xb @ WcatT^T  (M=4096, N=6144, K=2048)
    gemm_bt<<<dim3(48, 32), blk, 0, stream>>>(xb, WcatT, nullptr, qkvg, M_, ND_, HD_);
    tr_v<<<dim3(64, 128), blk, 0, stream>>>(qkvg, vT);

    gemm_n16<<<M_ / 16, blk, 0, stream>>>(x, Wgk1, T);
    gk_act<<<(M_ * KD_) / 256, blk, 0, stream>>>(T, Wgk2, bgk2, gkb);
    gate_prep<<<(B_ * H_ * NCHUNK_ * DK_) / 256, blk, 0, stream>>>(qkvg, gkb, qg, kg, kgT, gle);

    pass_c1<<<256, blk, 0, stream>>>(qg, kg, Asg);
    pass_a<<<dim3(2, 4, 256), blk, 0, stream>>>(kgT, vT, DtSt);
    pass_b<<<512, blk, 0, stream>>>(DtSt, gle);
    pass_c2<<<dim3(2, 1, 256), blk, 0, stream>>>(qg, vT, Asg, DtSt, o);
    postnorm<<<M_, blk, 0, stream>>>(o, qkvg, gnw, obf);
    gemm_bt<<<dim3(16, 32), blk, 0, stream>>>(obf, WotT, out, nullptr, M_, HD_, VD_);
}